// Round 11
// baseline (318.906 us; speedup 1.0000x reference)
//
#include <hip/hip_runtime.h>
#include <hip/hip_bf16.h>
#include <stdint.h>

typedef __hip_bfloat16 bf16;

using sh8    = __attribute__((ext_vector_type(8)))  short;
using sh4    = __attribute__((ext_vector_type(4)))  short;
using us4    = __attribute__((ext_vector_type(4)))  unsigned short;
using f32x16 = __attribute__((ext_vector_type(16))) float;
using fx4    = __attribute__((ext_vector_type(4)))  float;
using i32x2  = __attribute__((ext_vector_type(2)))  int;

#define NN    4096
#define NODES 8192
#define DIM   128
#define MD    16
#define KNNK  32
#define H1N   530
#define CPAD  544      // H1N padded to 17*32
#define PROW  1088     // [Pi 544 | Pj 544] per node, bf16

// weight-image offsets (in shorts)
#define OFF_W1AB 0      // [2][544][8]: half0 = W1f rows f0..7; half1 = [W1f8,0..0]
#define OFF_WE2A 8704   // [o][c] s=552  8832
#define OFF_WC1A 17536  // [u][k] s=32   2048
#define OFF_BE2  19584  // fp32[16]        32
#define OFF_BC1  19616  // fp32[64]       128
#define OFF_WC2  19744  // fp32[64]       128
#define OFF_BC2  19872  // fp32[4]          8
#define WIMG_SH  19880

__device__ __forceinline__ float b2f(bf16 x){ return __bfloat162float(x); }
__device__ __forceinline__ bf16  f2b(float x){ return __float2bfloat16(x); }
// fast silu: v_rcp_f32 (~1 ulp) instead of IEEE division
__device__ __forceinline__ float silu_f(float x){
    return x * __builtin_amdgcn_rcpf(1.f + __expf(-x));
}

__device__ __forceinline__ unsigned short f2us(float f){
    unsigned x = __float_as_uint(f);
    unsigned r = x + 0x7FFFu + ((x >> 16) & 1u);
    return (unsigned short)(r >> 16);
}
__device__ __forceinline__ float us2f(unsigned short u){
    return __uint_as_float(((unsigned)u) << 16);
}
// packed fp32x2 -> bf16x2; low short = a
__device__ __forceinline__ unsigned pkbf(float a, float b){
    __hip_bfloat162 v = __float22bfloat162_rn(make_float2(a, b));
    return *(unsigned*)&v;
}
// v_permlane32_swap_b32: new_a = [a.lo | b.lo], new_b = [a.hi | b.hi]
__device__ __forceinline__ void plswap(unsigned &a, unsigned &b){
    i32x2 r = __builtin_amdgcn_permlane32_swap((int)a, (int)b, false, false);
    a = (unsigned)r[0]; b = (unsigned)r[1];
}
__device__ __forceinline__ sh8 mk8(unsigned a, unsigned b, unsigned c, unsigned d){
    union { unsigned u[4]; sh8 s; } x;
    x.u[0] = a; x.u[1] = b; x.u[2] = c; x.u[3] = d;
    return x.s;
}
// flag-inline dtype read: fl=1 -> fp32 source, fl=0 -> bf16 source
__device__ __forceinline__ float ldconv(const void* p, int fl, size_t i){
    return fl ? ((const float*)p)[i] : b2f(((const bf16*)p)[i]);
}

struct Ptrs { const void* p[14]; int n[14]; };

// ---------------------------------------------------------------- K0: dtype detect
__global__ __launch_bounds__(256) void detect_kernel(Ptrs ps, int* flags){
    int tn = blockIdx.x;
    const bf16* s = (const bf16*)ps.p[tn];
    int n = ps.n[tn]; if (n > 8192) n = 8192;
    int bad = 0;
    for (int i = threadIdx.x; i < n; i += 256){
        float v = b2f(s[i]);
        if (!(fabsf(v) <= 64.f)) bad = 1;   // catches NaN/Inf too
    }
    __shared__ int sbad;
    if (threadIdx.x == 0) sbad = 0;
    __syncthreads();
    if (bad) atomicOr(&sbad, 1);
    __syncthreads();
    if (threadIdx.x == 0) flags[tn] = sbad;   // 1 = fp32, 0 = bf16
}

// ---------------------------------------------------------------- K1: prep_all (R5 verbatim)
#define PREP_TOTAL 1340352
__global__ __launch_bounds__(256) void prep_all(Ptrs ps, const int* __restrict__ flags,
        unsigned short* __restrict__ gwimg, unsigned short* __restrict__ We1T,
        unsigned short* __restrict__ fBF,   float* __restrict__ coorsF,
        float* __restrict__ be1F,  float* __restrict__ Wn1F,
        float* __restrict__ bn1F,  float* __restrict__ Wn2F,
        float* __restrict__ bn2F,  float* __restrict__ coorsS){
    int gid = blockIdx.x * 256 + threadIdx.x;
    if (gid < 4352){                         // W1AB half0: [c][f0..7]
        int c = gid >> 3, f = gid & 7;
        gwimg[OFF_W1AB + gid] =
            (c < H1N) ? f2us(ldconv(ps.p[2], flags[2], (size_t)(256 + f) * H1N + c)) : 0;
    } else if (gid < 8704){                  // W1AB half1: [c][W1f8,0,...]
        int e = gid - 4352; int c = e >> 3, jj = e & 7;
        gwimg[OFF_W1AB + 4352 + e] =
            (jj == 0 && c < H1N) ? f2us(ldconv(ps.p[2], flags[2], (size_t)264 * H1N + c)) : 0;
    } else if (gid < 17536){                 // We2^T s=552
        int e = gid - 8704; int o = e / 552, c = e - o * 552;
        gwimg[OFF_WE2A + e] =
            (c < H1N) ? f2us(ldconv(ps.p[4], flags[4], (size_t)c * 16 + o)) : 0;
    } else if (gid < 19584){                 // Wc1^T s=32
        int e = gid - 17536; int u = e >> 5, k = e & 31;
        gwimg[OFF_WC1A + e] =
            (k < 16) ? f2us(ldconv(ps.p[6], flags[6], (size_t)k * 64 + u)) : 0;
    } else if (gid < 19600){
        ((float*)(gwimg + OFF_BE2))[gid - 19584] = ldconv(ps.p[5], flags[5], gid - 19584);
    } else if (gid < 19664){
        ((float*)(gwimg + OFF_BC1))[gid - 19600] = ldconv(ps.p[7], flags[7], gid - 19600);
    } else if (gid < 19728){
        ((float*)(gwimg + OFF_WC2))[gid - 19664] = ldconv(ps.p[8], flags[8], gid - 19664);
    } else if (gid < 19732){
        int z = gid - 19728;
        ((float*)(gwimg + OFF_BC2))[z] = (z == 0) ? ldconv(ps.p[9], flags[9], 0) : 0.f;
    } else if (gid >= 32768 && gid < 172032){
        int e = gid - 32768; int n = e >> 7, k = e & 127;
        float v;
        if (n < CPAD) v = (n < H1N) ? ldconv(ps.p[2], flags[2], (size_t)k * H1N + n) : 0.f;
        else { int n2 = n - CPAD;
               v = (n2 < H1N) ? ldconv(ps.p[2], flags[2], (size_t)(128 + k) * H1N + n2) : 0.f; }
        We1T[e] = f2us(v);
    } else if (gid >= 172032 && gid < 1220608){
        int e = gid - 172032;
        fBF[e] = f2us(ldconv(ps.p[0], flags[0], e));
    } else if (gid >= 1220608 && gid < 1245184){
        int e = gid - 1220608;
        coorsF[e] = ldconv(ps.p[1], flags[1], e);
    } else if (gid >= 1245184 && gid < 1245714){
        int e = gid - 1245184;
        be1F[e] = ldconv(ps.p[3], flags[3], e);
    } else if (gid >= 1245760 && gid < 1282624){
        int e = gid - 1245760;
        Wn1F[e] = ldconv(ps.p[10], flags[10], e);
    } else if (gid >= 1282624 && gid < 1282880){
        int e = gid - 1282624;
        bn1F[e] = ldconv(ps.p[11], flags[11], e);
    } else if (gid >= 1282880 && gid < 1315648){
        int e = gid - 1282880;
        Wn2F[e] = ldconv(ps.p[12], flags[12], e);
    } else if (gid >= 1315648 && gid < 1315776){
        int e = gid - 1315648;
        bn2F[e] = ldconv(ps.p[13], flags[13], e);
    } else if (gid >= 1315776 && gid < 1340352){
        int e = gid - 1315776;            // source linear: ((b*NN+i)*3 + c)
        int n = e / 3, c = e - n * 3;     // n = global node, c = component
        coorsS[(size_t)c * NODES + n] = ldconv(ps.p[1], flags[1], e);
    }
}

// ---------------------------------------------------------------- K2: P-GEMM (R5 verbatim)
__global__ __launch_bounds__(256) void p_gemm(const unsigned short* __restrict__ fBF,
                                              const unsigned short* __restrict__ We1T,
                                              const float* __restrict__ be1,
                                              unsigned short* __restrict__ P){
    int t = threadIdx.x, lane = t & 63, wid = t >> 6;
    int e31 = lane & 31, hi = lane >> 5;
    int mW = (blockIdx.x << 7) + (wid << 5);
    int n0 = blockIdx.y << 5;

    const unsigned short* Arow = fBF  + (size_t)(mW + e31) * DIM + hi * 8;
    const unsigned short* Brow = We1T + (size_t)(n0 + e31) * DIM + hi * 8;

    f32x16 acc = {0.f,0.f,0.f,0.f,0.f,0.f,0.f,0.f,0.f,0.f,0.f,0.f,0.f,0.f,0.f,0.f};
    #pragma unroll
    for (int kc = 0; kc < 8; ++kc){
        sh8 a  = *(const sh8*)(Arow + kc * 16);
        sh8 bv = *(const sh8*)(Brow + kc * 16);
        acc = __builtin_amdgcn_mfma_f32_32x32x16_bf16(a, bv, acc, 0, 0, 0);
    }
    int n = n0 + e31;
    float beadd = 0.f;
    if (n < CPAD) beadd = (n < H1N) ? be1[n] : 0.f;   // fold be1 into Pi half
    #pragma unroll
    for (int g = 0; g < 4; ++g)
        #pragma unroll
        for (int r = 0; r < 4; ++r){
            int m = mW + 8*g + 4*hi + r;
            P[(size_t)m * PROW + n] = f2us(acc[4*g + r] + beadd);
        }
}

// ---------------------------------------------------------------- K3: KNN + edges fused (8 nodes/block)
// R8 structure (best measured: 250.96 total, edge_knn 114.2, LDS 39424,
// occupancy 46.7%). R11 change: knn pass 2 classifies from a REGISTER
// byte-cache wcache[16] (packed coarse buckets bk>>2, filled in pass 1 with
// fully-unrolled compile-time indexing) — R10's L1-stream saving (FETCH
// 54.6->49.5 MB was real) WITHOUT R10's +32 KB LDS occupancy loss.
// Coarse-boundary points (~16/node) recompute exactly from L2-resident
// coords; tie-break and nb>64 exact fallback unchanged.
__global__ __launch_bounds__(512, 6) void edge_knn(
        const float* __restrict__ coorsF, const float* __restrict__ coorsS,
        const unsigned short* __restrict__ gw,
        const unsigned short* __restrict__ P,
        float* __restrict__ mi_out, void* __restrict__ dout,
        const int* __restrict__ flagp){
    __shared__ __align__(16) union ShU {
        struct { unsigned hist[8][1024]; unsigned long long blist[8][64]; } k;  // 36.9 KB
        struct { unsigned short sWe2[16*552]; unsigned short trans[8][1280]; } e; // 38.1 KB
    } sh;
    __shared__ int idxw[8][32];          // knn output, wave-local
    __shared__ int cntO[8], cntB[8];

    int t = threadIdx.x, lane = t & 63, wid = t >> 6;
    int gnode = (blockIdx.x << 3) + wid;
    int b = gnode >> 12;
    int e31 = lane & 31, hi = lane >> 5;
    int e15 = lane & 15, q  = lane >> 4;

    // ================= phase A: knn (wave-autonomous radix select) =================
    {
        int i = gnode & (NN - 1);
        const float* cx = coorsS + (size_t)b * NN;
        const float* cy = coorsS + NODES + (size_t)b * NN;
        const float* cz = coorsS + 2 * NODES + (size_t)b * NN;

        float qx = cx[i], qy = cy[i], qz = cz[i];

        unsigned* h = &sh.k.hist[wid][0];
        {   // zero private hist: 4 x uint4 per lane (1024 bins)
            uint4* hz = (uint4*)h;
            uint4 z = make_uint4(0,0,0,0);
            #pragma unroll
            for (int zl = 0; zl < 4; ++zl) hz[zl * 64 + lane] = z;
        }
        if (lane == 0){ cntO[wid] = 0; cntB[wid] = 0; }
        asm volatile("" ::: "memory");

        unsigned wcache[16];   // 4 coarse buckets (bk>>2) per word, reg-resident

        // pass 1: distances -> bucket -> histogram + register byte-cache
        #pragma unroll
        for (int s = 0; s < 16; ++s){
            int j0 = (s << 8) + (lane << 2);
            fx4 X = *(const fx4*)(cx + j0);
            fx4 Y = *(const fx4*)(cy + j0);
            fx4 Z = *(const fx4*)(cz + j0);
            unsigned w = 0;
            #pragma unroll
            for (int k = 0; k < 4; ++k){
                float dx = qx - X[k], dy = qy - Y[k], dz = qz - Z[k];
                float d  = dx*dx + dy*dy + dz*dz;
                float d2 = d * d;
                unsigned bk = __float_as_uint(d2 * d2) >> 22;
                atomicAdd(&h[bk], 1u);
                w |= (bk >> 2) << (8 * k);
            }
            wcache[s] = w;
        }
        asm volatile("s_waitcnt lgkmcnt(0)" ::: "memory");

        // intra-wave scan: lane owns bins [lane*16, lane*16+16)
        unsigned S = 0;
        {
            uint4* hz = (uint4*)h;
            #pragma unroll
            for (int g = 0; g < 4; ++g){
                uint4 v = hz[lane * 4 + g];
                S += v.x + v.y + v.z + v.w;
            }
        }
        unsigned scan = S;
        #pragma unroll
        for (int off = 1; off < 64; off <<= 1){
            unsigned nv = __shfl_up(scan, off);
            if (lane >= off) scan += nv;
        }
        unsigned excl = scan - S;
        unsigned long long own = __ballot(excl < KNNK && excl + S >= KNNK);
        int src = __ffsll((unsigned long long)own) - 1;
        unsigned run = excl, Bloc = 0, below_l = 0;
        #pragma unroll
        for (int r = 0; r < 16; ++r){
            unsigned c = h[lane * 16 + r];
            if (run < KNNK && run + c >= KNNK){ Bloc = lane * 16 + r; below_l = run; }
            run += c;
        }
        unsigned B    = __shfl(Bloc, src);
        unsigned below= __shfl(below_l, src);
        unsigned need = KNNK - below;
        unsigned Bc = B >> 2;

        // pass 2: classify from register cache; exact only at the coarse boundary
        int* co = &cntO[wid];
        int* cbn = &cntB[wid];
        unsigned long long* bl = &sh.k.blist[wid][0];
        int* iw = &idxw[wid][0];
        #pragma unroll
        for (int s = 0; s < 16; ++s){
            unsigned w = wcache[s];
            #pragma unroll
            for (int k = 0; k < 4; ++k){
                unsigned bc = (w >> (8 * k)) & 255u;
                int j = (s << 8) + (lane << 2) + k;
                if (bc < Bc){                    // bk <= bc*4+3 < Bc*4 <= B
                    int pos = atomicAdd(co, 1);
                    iw[pos] = j;
                } else if (bc == Bc){            // ambiguous: recompute exactly
                    float dx = qx - cx[j], dy = qy - cy[j], dz = qz - cz[j];
                    float d  = dx*dx + dy*dy + dz*dz;
                    float d2 = d * d;
                    unsigned bk = __float_as_uint(d2 * d2) >> 22;
                    if (bk < B){
                        int pos = atomicAdd(co, 1);
                        iw[pos] = j;
                    } else if (bk == B){
                        unsigned long long mk = ((unsigned long long)__float_as_uint(d) << 32)
                                                | (unsigned)j;
                        int p = atomicAdd(cbn, 1);
                        if (p < 64) bl[p] = mk;
                    }
                }
            }
        }
        asm volatile("s_waitcnt lgkmcnt(0) vmcnt(0)" ::: "memory");
        int nb = *cbn;   // same-wave LDS in-order

        if (nb <= 64){
            unsigned long long e = (lane < nb) ? bl[lane] : ~0ull;
            for (unsigned r = 0; r < need; ++r){
                unsigned long long m = e;
                #pragma unroll
                for (int off = 32; off > 0; off >>= 1){
                    unsigned long long o = __shfl_xor(m, off);
                    if (o < m) m = o;
                }
                if (lane == 0)
                    iw[below + r] = (int)(unsigned)(m & 0xffffffffull);
                if (e == m) e = ~0ull;
            }
        } else {
            // ~never: boundary bin overflowed the list — exact full-rescan selection
            unsigned long long lastk = 0;
            for (unsigned r = 0; r < need; ++r){
                unsigned long long lmin = ~0ull;
                for (int s = 0; s < 64; ++s){
                    int j = (s << 6) + lane;
                    float dx = qx - cx[j];
                    float dy = qy - cy[j];
                    float dz = qz - cz[j];
                    float d  = dx*dx + dy*dy + dz*dz;
                    float d2 = d * d;
                    if ((__float_as_uint(d2 * d2) >> 22) == B){
                        unsigned long long mk = (((unsigned long long)__float_as_uint(d) << 32)
                                                 | (unsigned)j) + 1ull;
                        if (mk > lastk && mk < lmin) lmin = mk;
                    }
                }
                #pragma unroll
                for (int off = 32; off > 0; off >>= 1){
                    unsigned long long o = __shfl_xor(lmin, off);
                    if (o < lmin) lmin = o;
                }
                if (lane == 0)
                    iw[below + r] = (int)(unsigned)((lmin - 1ull) & 0xffffffffull);
                lastk = lmin;
            }
        }
    }

    __syncthreads();   // ALL waves done with sh.k before sWe2 overwrites it

    {   // stage We2^T (coalesced float4 copy) into the aliased region
        const float4* s1 = (const float4*)(gw + OFF_WE2A);
        float4* d1 = (float4*)sh.e.sWe2;
        for (int e = t; e < 1104; e += 512) d1[e] = s1[e];
    }

    // ================= phase B: edge pipeline (R8 verbatim) =================
    const float* cb = coorsF + (size_t)b * NN * 3;
    int i = gnode & (NN - 1);
    float qx = cb[i*3+0], qy = cb[i*3+1], qz = cb[i*3+2];

    int jme = idxw[wid][e31];            // same-wave write, in-order visible
    float rx = qx - cb[jme*3+0];
    float ry = qy - cb[jme*3+1];
    float rz = qz - cb[jme*3+2];
    float d = rx*rx + ry*ry + rz*rz;

    // fourier: sincos at d/8, then 3 angle doublings (err << bf16 mantissa)
    float s8v, c8v;
    __sincosf(d * 0.125f, &s8v, &c8v);
    float s4  = 2.f*s8v*c8v, c4  = 1.f - 2.f*s8v*s8v;
    float s2a = 2.f*s4*c4,   c2a = 1.f - 2.f*s4*s4;
    float s1a = 2.f*s2a*c2a, c1a = 1.f - 2.f*s2a*s2a;

    unsigned frb[9];
    frb[0] = f2us(s1a); frb[1] = f2us(s2a); frb[2] = f2us(s4); frb[3] = f2us(s8v);
    frb[4] = f2us(c1a); frb[5] = f2us(c2a); frb[6] = f2us(c4); frb[7] = f2us(c8v);
    frb[8] = f2us(d);

    // hi=0: B[k=0..7][e] = fourier; hi=1: B[8][e]=d, B[9][e]=1.0 (Pi slot)
    sh8 bfragC;
    #pragma unroll
    for (int j = 0; j < 8; ++j)
        bfragC[j] = (hi == 0) ? (short)frb[j]
                  : (short)((j == 0) ? frb[8] : (j == 1) ? 0x3F80u : 0u);

    // coalesced Pj staging: lane covers row (lane>>2) and row 16+(lane>>2),
    // 16 B each at quarter (lane&3); 16B granule XOR-swizzled by (row>>3).
    int nbase = gnode & ~(NN - 1);
    int j0 = __shfl(jme, lane >> 2);
    int j1 = __shfl(jme, 16 + (lane >> 2));
    const unsigned short* Pst0 = P + (size_t)(nbase + j0) * PROW + CPAD + (lane & 3) * 8;
    const unsigned short* Pst1 = P + (size_t)(nbase + j1) * PROW + CPAD + (lane & 3) * 8;
    const unsigned short* Pirow = P + (size_t)gnode * PROW;

    unsigned short* stg = &sh.e.trans[wid][0];            // stride 40 shorts
    int r0 = lane >> 2, r1 = 16 + (lane >> 2), qq = lane & 3;
    unsigned short* sw0 = stg + r0 * 40 + ((qq ^ (r0 >> 3)) << 3);
    unsigned short* sw1 = stg + r1 * 40 + ((qq ^ (r1 >> 3)) << 3);

    const float* g_be2 = (const float*)(gw + OFF_BE2);
    const float* g_bc1 = (const float*)(gw + OFF_BC1);
    const float* g_wc2 = (const float*)(gw + OFF_WC2);
    const float* g_bc2 = (const float*)(gw + OFF_BC2);

    f32x16 accD = {0.f,0.f,0.f,0.f,0.f,0.f,0.f,0.f,
                   0.f,0.f,0.f,0.f,0.f,0.f,0.f,0.f};

    // pipeline: chunk 0's Pj lines in flight before the barrier
    sh8 g0v = *(const sh8*)(Pst0);
    sh8 g1v = *(const sh8*)(Pst1);

    // swizzled cc read offsets (granule g at physical g ^ (e31>>3), +4*hi shorts)
    int sx = e31 >> 3;
    const unsigned short* ccb = stg + e31 * 40 + 4 * hi;

    __syncthreads();   // staged weights visible

    #pragma unroll 1
    for (int ch = 0; ch < 17; ++ch){
        int c0 = ch * 32;
        *(sh8*)sw0 = g0v;                                  // ds_write_b128 x2
        *(sh8*)sw1 = g1v;
        if (ch < 16){   // issue next chunk's lines now; latency hides under body
            g0v = *(const sh8*)(Pst0 + c0 + 32);
            g1v = *(const sh8*)(Pst1 + c0 + 32);
        }

        unsigned short piS = Pirow[c0 + e31];
        sh8 afrag = *(const sh8*)(gw + OFF_W1AB + (size_t)(hi * 544 + c0 + e31) * 8);
        afrag[1] = hi ? (short)piS : afrag[1];            // Pi into k=9 slot

        // C-init = Pj (same-wave DS pipe is in-order: reads see the writes)
        f32x16 cc;
        #pragma unroll
        for (int g = 0; g < 4; ++g){
            us4 pj = *(const us4*)(ccb + ((g ^ sx) << 3));
            cc[4*g+0] = us2f(pj.x);
            cc[4*g+1] = us2f(pj.y);
            cc[4*g+2] = us2f(pj.z);
            cc[4*g+3] = us2f(pj.w);
        }
        f32x16 h = __builtin_amdgcn_mfma_f32_32x32x16_bf16(afrag, bfragC, cc, 0, 0, 0);

        // silu -> bf16 pairs; lane holds (edge=e31, ch pairs at +4*hi)
        unsigned u0 = pkbf(silu_f(h[0]),  silu_f(h[1]));
        unsigned u1 = pkbf(silu_f(h[2]),  silu_f(h[3]));
        unsigned u2 = pkbf(silu_f(h[4]),  silu_f(h[5]));
        unsigned u3 = pkbf(silu_f(h[6]),  silu_f(h[7]));
        unsigned u4 = pkbf(silu_f(h[8]),  silu_f(h[9]));
        unsigned u5 = pkbf(silu_f(h[10]), silu_f(h[11]));
        unsigned u6 = pkbf(silu_f(h[12]), silu_f(h[13]));
        unsigned u7 = pkbf(silu_f(h[14]), silu_f(h[15]));
        // in-register h^T A-frag: swap lower/upper wave halves
        plswap(u0, u2); plswap(u1, u3);    // K-half ch c0+0..15
        plswap(u4, u6); plswap(u5, u7);    // K-half ch c0+16..31
        sh8 A1 = mk8(u0, u1, u2, u3);
        sh8 A2 = mk8(u4, u5, u6, u7);

        // B = We2 from LDS: B[k=ch][col=out o]; cols 16-31 clamp to rows 0-15
        const unsigned short* wrow = &sh.e.sWe2[(size_t)(e31 & 15) * 552 + c0 + (hi << 3)];
        sh8 B1 = *(const sh8*)(wrow);
        sh8 B2 = *(const sh8*)(wrow + 16);
        accD = __builtin_amdgcn_mfma_f32_32x32x16_bf16(A1, B1, accD, 0, 0, 0);
        accD = __builtin_amdgcn_mfma_f32_32x32x16_bf16(A2, B2, accD, 0, 0, 0);
    }

    // ---- m = silu(OUT2 + be2): lane = out channel o (o<16 valid),
    //      rows = edges (r&3)+8*(r>>2)+4*hi ----
    float be2v = g_be2[e31 & 15];
    float mval[16];
    float msum = 0.f;
    #pragma unroll
    for (int r = 0; r < 16; ++r){
        mval[r] = silu_f(accD[r] + be2v);
        msum += mval[r];
    }
    msum += __shfl_xor(msum, 32);        // partner holds complementary edges

    if (e31 < 16){
        // one-time transpose into sM[edge][o] (bf16), for phase E's B-frags
        #pragma unroll
        for (int r = 0; r < 16; ++r){
            int edge = (r & 3) + 8 * (r >> 2) + 4 * hi;
            stg[edge * 16 + e31] = f2us(mval[r]);
        }
        if (hi == 0)
            mi_out[(size_t)gnode * MD + e31] = msum;   // 16 coalesced stores
    }

    // ---- phase E: coors MLP (reads sM written above; same-wave DS order) ----
    float tsum0 = 0.f, tsum1 = 0.f;
    #pragma unroll
    for (int ut = 0; ut < 4; ++ut){
        sh8 wa3 = *(const sh8*)(gw + OFF_WC1A + (size_t)(ut * 16 + e15) * 32 + q * 8);
        sh8 b0  = (q < 2) ? *(const sh8*)&stg[e15 * 16 + q * 8]        : (sh8)0;
        sh8 b1  = (q < 2) ? *(const sh8*)&stg[(16 + e15) * 16 + q * 8] : (sh8)0;
        fx4 a0 = {0.f,0.f,0.f,0.f};
        fx4 a1 = {0.f,0.f,0.f,0.f};
        a0 = __builtin_amdgcn_mfma_f32_16x16x32_bf16(wa3, b0, a0, 0, 0, 0);
        a1 = __builtin_amdgcn_mfma_f32_16x16x32_bf16(wa3, b1, a1, 0, 0, 0);
        fx4 bc1q = *(const fx4*)&g_bc1[ut * 16 + q * 4];
        fx4 wcq  = *(const fx4*)&g_wc2[ut * 16 + q * 4];
        #pragma unroll
        for (int r = 0; r < 4; ++r){
            tsum0 += silu_f(a0[r] + bc1q[r]) * wcq[r];
            tsum1 += silu_f(a1[r] + bc1q[r]) * wcq[r];
        }
    }
    tsum0 += __shfl_xor(tsum0, 16); tsum0 += __shfl_xor(tsum0, 32);
    tsum1 += __shfl_xor(tsum1, 16); tsum1 += __shfl_xor(tsum1, 32);
    float cw = ((lane < 16) ? tsum0 : tsum1) + g_bc2[0];

    // lanes 0..31 hold edges 0..31; mask the duplicate upper half
    float en = (lane < 32) ? 1.f : 0.f;
    float cx2 = en * cw * rx, cy2 = en * cw * ry, cz2 = en * cw * rz;
    #pragma unroll
    for (int off = 1; off <= 32; off <<= 1){
        cx2 += __shfl_xor(cx2, off);
        cy2 += __shfl_xor(cy2, off);
        cz2 += __shfl_xor(cz2, off);
    }
    if (lane == 0){
        size_t base = (size_t)NODES * DIM + (size_t)gnode * 3;
        if (*flagp){
            float* o = (float*)dout;
            o[base+0] = cx2 + qx; o[base+1] = cy2 + qy; o[base+2] = cz2 + qz;
        } else {
            bf16* o = (bf16*)dout;
            o[base+0] = f2b(cx2 + qx); o[base+1] = f2b(cy2 + qy); o[base+2] = f2b(cz2 + qz);
        }
    }
}

// ---------------------------------------------------------------- K4: node MLP (R5/R8 verbatim, 1024 blocks)
__global__ __launch_bounds__(256) void node_kernel(
        const void* __restrict__ featsRaw, const float* __restrict__ m_i,
        const float* __restrict__ Wn1,   const float* __restrict__ bn1,
        const float* __restrict__ Wn2,   const float* __restrict__ bn2,
        void* __restrict__ dout,         const int* __restrict__ flagp){
    __shared__ __align__(16) float X[8][144];
    __shared__ __align__(16) float Hs[8][256];
    int t = threadIdx.x;
    int g0 = blockIdx.x << 3;
    int fl = flagp[0];

    for (int e = t; e < 8 * DIM; e += 256){
        int nd = e >> 7, c = e & 127;
        size_t off = (size_t)(g0 + nd) * DIM + c;
        X[nd][c] = fl ? ((const float*)featsRaw)[off]
                      : b2f(((const bf16*)featsRaw)[off]);
    }
    if (t < 128){
        int nd = t >> 4, c = t & 15;
        X[nd][DIM + c] = m_i[(size_t)(g0 + nd) * MD + c];
    }
    __syncthreads();

    float acc[8] = {};
    for (int r4 = 0; r4 < 144; r4 += 4){
        float w0 = Wn1[(size_t)(r4+0) * 256 + t];
        float w1 = Wn1[(size_t)(r4+1) * 256 + t];
        float w2 = Wn1[(size_t)(r4+2) * 256 + t];
        float w3 = Wn1[(size_t)(r4+3) * 256 + t];
        #pragma unroll
        for (int nd = 0; nd < 8; ++nd){
            fx4 x4 = *(const fx4*)&X[nd][r4];          // ds_read_b128
            acc[nd] += x4[0]*w0 + x4[1]*w1 + x4[2]*w2 + x4[3]*w3;
        }
    }
    float bb = bn1[t];
    #pragma unroll
    for (int nd = 0; nd < 8; ++nd) Hs[nd][t] = silu_f(acc[nd] + bb);
    __syncthreads();

    int c = t & 127, g = t >> 7;
    float a2[4] = {};
    for (int r4 = 0; r4 < 256; r4 += 4){
        float w0 = Wn2[(size_t)(r4+0) * DIM + c];
        float w1 = Wn2[(size_t)(r4+1) * DIM + c];
        float w2 = Wn2[(size_t)(r4+2) * DIM + c];
        float w3 = Wn2[(size_t)(r4+3) * DIM + c];
        #pragma unroll
        for (int u = 0; u < 4; ++u){
            fx4 h4 = *(const fx4*)&Hs[g*4 + u][r4];    // ds_read_b128
            a2[u] += h4[0]*w0 + h4[1]*w1 + h4[2]*w2 + h4[3]*w3;
        }
    }
    float b2v = bn2[c];
    #pragma unroll
    for (int u = 0; u < 4; ++u){
        int nd = g*4 + u;
        float v = a2[u] + b2v + X[nd][c];
        size_t off2 = (size_t)(g0 + nd) * DIM + c;
        if (fl) ((float*)dout)[off2] = v;
        else    ((bf16*)dout)[off2]  = f2b(v);
    }
}

// ---------------------------------------------------------------- launch
extern "C" void kernel_launch(void* const* d_in, const int* in_sizes, int n_in,
                              void* d_out, int out_size, void* d_ws, size_t ws_size,
                              hipStream_t stream){
    char* ws = (char*)d_ws;
    size_t off = 0;
    auto alloc = [&](size_t bytes) -> char* {
        off = (off + 511) & ~(size_t)511;
        char* p = ws + off;
        off += bytes;
        return p;
    };

    int* flags = (int*)alloc(14 * 4);
    unsigned short* gwimg = (unsigned short*)alloc((size_t)WIMG_SH * 2);
    unsigned short* We1T  = (unsigned short*)alloc((size_t)1088 * 128 * 2);
    unsigned short* fBF   = (unsigned short*)alloc((size_t)NODES * DIM * 2);
    float* coorsF = (float*)alloc((size_t)2 * NN * 3 * 4);
    float* be1F   = (float*)alloc((size_t)544 * 4);
    float* Wn1F   = (float*)alloc((size_t)144 * 256 * 4);
    float* bn1F   = (float*)alloc((size_t)256 * 4);
    float* Wn2F   = (float*)alloc((size_t)256 * 128 * 4);
    float* bn2F   = (float*)alloc((size_t)128 * 4);
    float* coorsS = (float*)alloc((size_t)3 * NODES * 4);   // SoA planes x|y|z
    unsigned short* P = (unsigned short*) alloc((size_t)NODES * PROW * 2);  // 17.8 MB
    float* mi     = (float*)alloc((size_t)NODES * MD * 4);

    Ptrs ps;
    for (int i = 0; i < 14; ++i){ ps.p[i] = d_in[i]; ps.n[i] = in_sizes[i]; }

    detect_kernel<<<14, 256, 0, stream>>>(ps, flags);
    prep_all<<<(PREP_TOTAL + 255) / 256, 256, 0, stream>>>(
        ps, flags, gwimg, We1T, fBF, coorsF, be1F, Wn1F, bn1F, Wn2F, bn2F, coorsS);
    p_gemm<<<dim3(64, 34), 256, 0, stream>>>(fBF, We1T, be1F, P);
    edge_knn<<<NODES/8, 512, 0, stream>>>(coorsF, coorsS, gwimg, P, mi,
                                          d_out, flags + 0);
    node_kernel<<<1024, 256, 0, stream>>>(d_in[0], mi, Wn1F, bn1F, Wn2F, bn2F,
                                          d_out, flags + 0);
}

// Round 12
// 283.732 us; speedup vs baseline: 1.1240x; 1.1240x over previous
//
#include <hip/hip_runtime.h>
#include <hip/hip_bf16.h>
#include <stdint.h>

typedef __hip_bfloat16 bf16;

using sh8    = __attribute__((ext_vector_type(8)))  short;
using sh4    = __attribute__((ext_vector_type(4)))  short;
using us4    = __attribute__((ext_vector_type(4)))  unsigned short;
using f32x16 = __attribute__((ext_vector_type(16))) float;
using fx4    = __attribute__((ext_vector_type(4)))  float;
using i32x2  = __attribute__((ext_vector_type(2)))  int;

#define NN    4096
#define NODES 8192
#define DIM   128
#define MD    16
#define KNNK  32
#define H1N   530
#define CPAD  544      // H1N padded to 17*32
#define PROW  1088     // [Pi 544 | Pj 544] per node, bf16

// weight-image offsets (in shorts)
#define OFF_W1AB 0      // [2][544][8]: half0 = W1f rows f0..7; half1 = [W1f8,0..0]
#define OFF_WE2A 8704   // [o][c] s=552  8832
#define OFF_WC1A 17536  // [u][k] s=32   2048
#define OFF_BE2  19584  // fp32[16]        32
#define OFF_BC1  19616  // fp32[64]       128
#define OFF_WC2  19744  // fp32[64]       128
#define OFF_BC2  19872  // fp32[4]          8
#define WIMG_SH  19880

__device__ __forceinline__ float b2f(bf16 x){ return __bfloat162float(x); }
__device__ __forceinline__ bf16  f2b(float x){ return __float2bfloat16(x); }
// fast silu: v_rcp_f32 (~1 ulp) instead of IEEE division
__device__ __forceinline__ float silu_f(float x){
    return x * __builtin_amdgcn_rcpf(1.f + __expf(-x));
}

__device__ __forceinline__ unsigned short f2us(float f){
    unsigned x = __float_as_uint(f);
    unsigned r = x + 0x7FFFu + ((x >> 16) & 1u);
    return (unsigned short)(r >> 16);
}
__device__ __forceinline__ float us2f(unsigned short u){
    return __uint_as_float(((unsigned)u) << 16);
}
// packed fp32x2 -> bf16x2; low short = a
__device__ __forceinline__ unsigned pkbf(float a, float b){
    __hip_bfloat162 v = __float22bfloat162_rn(make_float2(a, b));
    return *(unsigned*)&v;
}
// v_permlane32_swap_b32: new_a = [a.lo | b.lo], new_b = [a.hi | b.hi]
__device__ __forceinline__ void plswap(unsigned &a, unsigned &b){
    i32x2 r = __builtin_amdgcn_permlane32_swap((int)a, (int)b, false, false);
    a = (unsigned)r[0]; b = (unsigned)r[1];
}
__device__ __forceinline__ sh8 mk8(unsigned a, unsigned b, unsigned c, unsigned d){
    union { unsigned u[4]; sh8 s; } x;
    x.u[0] = a; x.u[1] = b; x.u[2] = c; x.u[3] = d;
    return x.s;
}
// flag-inline dtype read: fl=1 -> fp32 source, fl=0 -> bf16 source
__device__ __forceinline__ float ldconv(const void* p, int fl, size_t i){
    return fl ? ((const float*)p)[i] : b2f(((const bf16*)p)[i]);
}

struct Ptrs { const void* p[14]; int n[14]; };

// ---------------------------------------------------------------- K0: dtype detect
__global__ __launch_bounds__(256) void detect_kernel(Ptrs ps, int* flags){
    int tn = blockIdx.x;
    const bf16* s = (const bf16*)ps.p[tn];
    int n = ps.n[tn]; if (n > 8192) n = 8192;
    int bad = 0;
    for (int i = threadIdx.x; i < n; i += 256){
        float v = b2f(s[i]);
        if (!(fabsf(v) <= 64.f)) bad = 1;   // catches NaN/Inf too
    }
    __shared__ int sbad;
    if (threadIdx.x == 0) sbad = 0;
    __syncthreads();
    if (bad) atomicOr(&sbad, 1);
    __syncthreads();
    if (threadIdx.x == 0) flags[tn] = sbad;   // 1 = fp32, 0 = bf16
}

// ---------------------------------------------------------------- K1: prep_all (R5 verbatim)
#define PREP_TOTAL 1340352
__global__ __launch_bounds__(256) void prep_all(Ptrs ps, const int* __restrict__ flags,
        unsigned short* __restrict__ gwimg, unsigned short* __restrict__ We1T,
        unsigned short* __restrict__ fBF,   float* __restrict__ coorsF,
        float* __restrict__ be1F,  float* __restrict__ Wn1F,
        float* __restrict__ bn1F,  float* __restrict__ Wn2F,
        float* __restrict__ bn2F,  float* __restrict__ coorsS){
    int gid = blockIdx.x * 256 + threadIdx.x;
    if (gid < 4352){                         // W1AB half0: [c][f0..7]
        int c = gid >> 3, f = gid & 7;
        gwimg[OFF_W1AB + gid] =
            (c < H1N) ? f2us(ldconv(ps.p[2], flags[2], (size_t)(256 + f) * H1N + c)) : 0;
    } else if (gid < 8704){                  // W1AB half1: [c][W1f8,0,...]
        int e = gid - 4352; int c = e >> 3, jj = e & 7;
        gwimg[OFF_W1AB + 4352 + e] =
            (jj == 0 && c < H1N) ? f2us(ldconv(ps.p[2], flags[2], (size_t)264 * H1N + c)) : 0;
    } else if (gid < 17536){                 // We2^T s=552
        int e = gid - 8704; int o = e / 552, c = e - o * 552;
        gwimg[OFF_WE2A + e] =
            (c < H1N) ? f2us(ldconv(ps.p[4], flags[4], (size_t)c * 16 + o)) : 0;
    } else if (gid < 19584){                 // Wc1^T s=32
        int e = gid - 17536; int u = e >> 5, k = e & 31;
        gwimg[OFF_WC1A + e] =
            (k < 16) ? f2us(ldconv(ps.p[6], flags[6], (size_t)k * 64 + u)) : 0;
    } else if (gid < 19600){
        ((float*)(gwimg + OFF_BE2))[gid - 19584] = ldconv(ps.p[5], flags[5], gid - 19584);
    } else if (gid < 19664){
        ((float*)(gwimg + OFF_BC1))[gid - 19600] = ldconv(ps.p[7], flags[7], gid - 19600);
    } else if (gid < 19728){
        ((float*)(gwimg + OFF_WC2))[gid - 19664] = ldconv(ps.p[8], flags[8], gid - 19664);
    } else if (gid < 19732){
        int z = gid - 19728;
        ((float*)(gwimg + OFF_BC2))[z] = (z == 0) ? ldconv(ps.p[9], flags[9], 0) : 0.f;
    } else if (gid >= 32768 && gid < 172032){
        int e = gid - 32768; int n = e >> 7, k = e & 127;
        float v;
        if (n < CPAD) v = (n < H1N) ? ldconv(ps.p[2], flags[2], (size_t)k * H1N + n) : 0.f;
        else { int n2 = n - CPAD;
               v = (n2 < H1N) ? ldconv(ps.p[2], flags[2], (size_t)(128 + k) * H1N + n2) : 0.f; }
        We1T[e] = f2us(v);
    } else if (gid >= 172032 && gid < 1220608){
        int e = gid - 172032;
        fBF[e] = f2us(ldconv(ps.p[0], flags[0], e));
    } else if (gid >= 1220608 && gid < 1245184){
        int e = gid - 1220608;
        coorsF[e] = ldconv(ps.p[1], flags[1], e);
    } else if (gid >= 1245184 && gid < 1245714){
        int e = gid - 1245184;
        be1F[e] = ldconv(ps.p[3], flags[3], e);
    } else if (gid >= 1245760 && gid < 1282624){
        int e = gid - 1245760;
        Wn1F[e] = ldconv(ps.p[10], flags[10], e);
    } else if (gid >= 1282624 && gid < 1282880){
        int e = gid - 1282624;
        bn1F[e] = ldconv(ps.p[11], flags[11], e);
    } else if (gid >= 1282880 && gid < 1315648){
        int e = gid - 1282880;
        Wn2F[e] = ldconv(ps.p[12], flags[12], e);
    } else if (gid >= 1315648 && gid < 1315776){
        int e = gid - 1315648;
        bn2F[e] = ldconv(ps.p[13], flags[13], e);
    } else if (gid >= 1315776 && gid < 1340352){
        int e = gid - 1315776;            // source linear: ((b*NN+i)*3 + c)
        int n = e / 3, c = e - n * 3;     // n = global node, c = component
        coorsS[(size_t)c * NODES + n] = ldconv(ps.p[1], flags[1], e);
    }
}

// ---------------------------------------------------------------- K2: P-GEMM (R5 verbatim)
__global__ __launch_bounds__(256) void p_gemm(const unsigned short* __restrict__ fBF,
                                              const unsigned short* __restrict__ We1T,
                                              const float* __restrict__ be1,
                                              unsigned short* __restrict__ P){
    int t = threadIdx.x, lane = t & 63, wid = t >> 6;
    int e31 = lane & 31, hi = lane >> 5;
    int mW = (blockIdx.x << 7) + (wid << 5);
    int n0 = blockIdx.y << 5;

    const unsigned short* Arow = fBF  + (size_t)(mW + e31) * DIM + hi * 8;
    const unsigned short* Brow = We1T + (size_t)(n0 + e31) * DIM + hi * 8;

    f32x16 acc = {0.f,0.f,0.f,0.f,0.f,0.f,0.f,0.f,0.f,0.f,0.f,0.f,0.f,0.f,0.f,0.f};
    #pragma unroll
    for (int kc = 0; kc < 8; ++kc){
        sh8 a  = *(const sh8*)(Arow + kc * 16);
        sh8 bv = *(const sh8*)(Brow + kc * 16);
        acc = __builtin_amdgcn_mfma_f32_32x32x16_bf16(a, bv, acc, 0, 0, 0);
    }
    int n = n0 + e31;
    float beadd = 0.f;
    if (n < CPAD) beadd = (n < H1N) ? be1[n] : 0.f;   // fold be1 into Pi half
    #pragma unroll
    for (int g = 0; g < 4; ++g)
        #pragma unroll
        for (int r = 0; r < 4; ++r){
            int m = mW + 8*g + 4*hi + r;
            P[(size_t)m * PROW + n] = f2us(acc[4*g + r] + beadd);
        }
}

// ---------------------------------------------------------------- K3: KNN + edges fused (8 nodes/block)
// R8 structure + R11's register byte-cache, now under __launch_bounds__(512,4):
// R11's spill (WRITE 293 MB, VGPR pinned at 40) was the (512,6) ~85-VGPR cap
// forcing wcache[16] to scratch. (512,4) raises the cap to 128; achievable
// occupancy is unchanged (R8 MEASURED 46.7% ~= 2 blocks/CU; 8-wave blocks
// quantize to 2 blocks at any VGPR <= ~100, LDS 39.4 KB allows 4).
__global__ __launch_bounds__(512, 4) void edge_knn(
        const float* __restrict__ coorsF, const float* __restrict__ coorsS,
        const unsigned short* __restrict__ gw,
        const unsigned short* __restrict__ P,
        float* __restrict__ mi_out, void* __restrict__ dout,
        const int* __restrict__ flagp){
    __shared__ __align__(16) union ShU {
        struct { unsigned hist[8][1024]; unsigned long long blist[8][64]; } k;  // 36.9 KB
        struct { unsigned short sWe2[16*552]; unsigned short trans[8][1280]; } e; // 38.1 KB
    } sh;
    __shared__ int idxw[8][32];          // knn output, wave-local
    __shared__ int cntO[8], cntB[8];

    int t = threadIdx.x, lane = t & 63, wid = t >> 6;
    int gnode = (blockIdx.x << 3) + wid;
    int b = gnode >> 12;
    int e31 = lane & 31, hi = lane >> 5;
    int e15 = lane & 15, q  = lane >> 4;

    // ================= phase A: knn (wave-autonomous radix select) =================
    {
        int i = gnode & (NN - 1);
        const float* cx = coorsS + (size_t)b * NN;
        const float* cy = coorsS + NODES + (size_t)b * NN;
        const float* cz = coorsS + 2 * NODES + (size_t)b * NN;

        float qx = cx[i], qy = cy[i], qz = cz[i];

        unsigned* h = &sh.k.hist[wid][0];
        {   // zero private hist: 4 x uint4 per lane (1024 bins)
            uint4* hz = (uint4*)h;
            uint4 z = make_uint4(0,0,0,0);
            #pragma unroll
            for (int zl = 0; zl < 4; ++zl) hz[zl * 64 + lane] = z;
        }
        if (lane == 0){ cntO[wid] = 0; cntB[wid] = 0; }
        asm volatile("" ::: "memory");

        unsigned wcache[16];   // 4 coarse buckets (bk>>2) per word, reg-resident

        // pass 1: distances -> bucket -> histogram + register byte-cache
        #pragma unroll
        for (int s = 0; s < 16; ++s){
            int j0 = (s << 8) + (lane << 2);
            fx4 X = *(const fx4*)(cx + j0);
            fx4 Y = *(const fx4*)(cy + j0);
            fx4 Z = *(const fx4*)(cz + j0);
            unsigned w = 0;
            #pragma unroll
            for (int k = 0; k < 4; ++k){
                float dx = qx - X[k], dy = qy - Y[k], dz = qz - Z[k];
                float d  = dx*dx + dy*dy + dz*dz;
                float d2 = d * d;
                unsigned bk = __float_as_uint(d2 * d2) >> 22;
                atomicAdd(&h[bk], 1u);
                w |= (bk >> 2) << (8 * k);
            }
            wcache[s] = w;
        }
        asm volatile("s_waitcnt lgkmcnt(0)" ::: "memory");

        // intra-wave scan: lane owns bins [lane*16, lane*16+16)
        unsigned S = 0;
        {
            uint4* hz = (uint4*)h;
            #pragma unroll
            for (int g = 0; g < 4; ++g){
                uint4 v = hz[lane * 4 + g];
                S += v.x + v.y + v.z + v.w;
            }
        }
        unsigned scan = S;
        #pragma unroll
        for (int off = 1; off < 64; off <<= 1){
            unsigned nv = __shfl_up(scan, off);
            if (lane >= off) scan += nv;
        }
        unsigned excl = scan - S;
        unsigned long long own = __ballot(excl < KNNK && excl + S >= KNNK);
        int src = __ffsll((unsigned long long)own) - 1;
        unsigned run = excl, Bloc = 0, below_l = 0;
        #pragma unroll
        for (int r = 0; r < 16; ++r){
            unsigned c = h[lane * 16 + r];
            if (run < KNNK && run + c >= KNNK){ Bloc = lane * 16 + r; below_l = run; }
            run += c;
        }
        unsigned B    = __shfl(Bloc, src);
        unsigned below= __shfl(below_l, src);
        unsigned need = KNNK - below;
        unsigned Bc = B >> 2;

        // pass 2: classify from register cache; exact only at the coarse boundary
        int* co = &cntO[wid];
        int* cbn = &cntB[wid];
        unsigned long long* bl = &sh.k.blist[wid][0];
        int* iw = &idxw[wid][0];
        #pragma unroll
        for (int s = 0; s < 16; ++s){
            unsigned w = wcache[s];
            #pragma unroll
            for (int k = 0; k < 4; ++k){
                unsigned bc = (w >> (8 * k)) & 255u;
                int j = (s << 8) + (lane << 2) + k;
                if (bc < Bc){                    // bk <= bc*4+3 < Bc*4 <= B
                    int pos = atomicAdd(co, 1);
                    iw[pos] = j;
                } else if (bc == Bc){            // ambiguous: recompute exactly
                    float dx = qx - cx[j], dy = qy - cy[j], dz = qz - cz[j];
                    float d  = dx*dx + dy*dy + dz*dz;
                    float d2 = d * d;
                    unsigned bk = __float_as_uint(d2 * d2) >> 22;
                    if (bk < B){
                        int pos = atomicAdd(co, 1);
                        iw[pos] = j;
                    } else if (bk == B){
                        unsigned long long mk = ((unsigned long long)__float_as_uint(d) << 32)
                                                | (unsigned)j;
                        int p = atomicAdd(cbn, 1);
                        if (p < 64) bl[p] = mk;
                    }
                }
            }
        }
        asm volatile("s_waitcnt lgkmcnt(0) vmcnt(0)" ::: "memory");
        int nb = *cbn;   // same-wave LDS in-order

        if (nb <= 64){
            unsigned long long e = (lane < nb) ? bl[lane] : ~0ull;
            for (unsigned r = 0; r < need; ++r){
                unsigned long long m = e;
                #pragma unroll
                for (int off = 32; off > 0; off >>= 1){
                    unsigned long long o = __shfl_xor(m, off);
                    if (o < m) m = o;
                }
                if (lane == 0)
                    iw[below + r] = (int)(unsigned)(m & 0xffffffffull);
                if (e == m) e = ~0ull;
            }
        } else {
            // ~never: boundary bin overflowed the list — exact full-rescan selection
            unsigned long long lastk = 0;
            for (unsigned r = 0; r < need; ++r){
                unsigned long long lmin = ~0ull;
                for (int s = 0; s < 64; ++s){
                    int j = (s << 6) + lane;
                    float dx = qx - cx[j];
                    float dy = qy - cy[j];
                    float dz = qz - cz[j];
                    float d  = dx*dx + dy*dy + dz*dz;
                    float d2 = d * d;
                    if ((__float_as_uint(d2 * d2) >> 22) == B){
                        unsigned long long mk = (((unsigned long long)__float_as_uint(d) << 32)
                                                 | (unsigned)j) + 1ull;
                        if (mk > lastk && mk < lmin) lmin = mk;
                    }
                }
                #pragma unroll
                for (int off = 32; off > 0; off >>= 1){
                    unsigned long long o = __shfl_xor(lmin, off);
                    if (o < lmin) lmin = o;
                }
                if (lane == 0)
                    iw[below + r] = (int)(unsigned)((lmin - 1ull) & 0xffffffffull);
                lastk = lmin;
            }
        }
    }

    __syncthreads();   // ALL waves done with sh.k before sWe2 overwrites it

    {   // stage We2^T (coalesced float4 copy) into the aliased region
        const float4* s1 = (const float4*)(gw + OFF_WE2A);
        float4* d1 = (float4*)sh.e.sWe2;
        for (int e = t; e < 1104; e += 512) d1[e] = s1[e];
    }

    // ================= phase B: edge pipeline (R8 verbatim) =================
    const float* cb = coorsF + (size_t)b * NN * 3;
    int i = gnode & (NN - 1);
    float qx = cb[i*3+0], qy = cb[i*3+1], qz = cb[i*3+2];

    int jme = idxw[wid][e31];            // same-wave write, in-order visible
    float rx = qx - cb[jme*3+0];
    float ry = qy - cb[jme*3+1];
    float rz = qz - cb[jme*3+2];
    float d = rx*rx + ry*ry + rz*rz;

    // fourier: sincos at d/8, then 3 angle doublings (err << bf16 mantissa)
    float s8v, c8v;
    __sincosf(d * 0.125f, &s8v, &c8v);
    float s4  = 2.f*s8v*c8v, c4  = 1.f - 2.f*s8v*s8v;
    float s2a = 2.f*s4*c4,   c2a = 1.f - 2.f*s4*s4;
    float s1a = 2.f*s2a*c2a, c1a = 1.f - 2.f*s2a*s2a;

    unsigned frb[9];
    frb[0] = f2us(s1a); frb[1] = f2us(s2a); frb[2] = f2us(s4); frb[3] = f2us(s8v);
    frb[4] = f2us(c1a); frb[5] = f2us(c2a); frb[6] = f2us(c4); frb[7] = f2us(c8v);
    frb[8] = f2us(d);

    // hi=0: B[k=0..7][e] = fourier; hi=1: B[8][e]=d, B[9][e]=1.0 (Pi slot)
    sh8 bfragC;
    #pragma unroll
    for (int j = 0; j < 8; ++j)
        bfragC[j] = (hi == 0) ? (short)frb[j]
                  : (short)((j == 0) ? frb[8] : (j == 1) ? 0x3F80u : 0u);

    // coalesced Pj staging: lane covers row (lane>>2) and row 16+(lane>>2),
    // 16 B each at quarter (lane&3); 16B granule XOR-swizzled by (row>>3).
    int nbase = gnode & ~(NN - 1);
    int j0 = __shfl(jme, lane >> 2);
    int j1 = __shfl(jme, 16 + (lane >> 2));
    const unsigned short* Pst0 = P + (size_t)(nbase + j0) * PROW + CPAD + (lane & 3) * 8;
    const unsigned short* Pst1 = P + (size_t)(nbase + j1) * PROW + CPAD + (lane & 3) * 8;
    const unsigned short* Pirow = P + (size_t)gnode * PROW;

    unsigned short* stg = &sh.e.trans[wid][0];            // stride 40 shorts
    int r0 = lane >> 2, r1 = 16 + (lane >> 2), qq = lane & 3;
    unsigned short* sw0 = stg + r0 * 40 + ((qq ^ (r0 >> 3)) << 3);
    unsigned short* sw1 = stg + r1 * 40 + ((qq ^ (r1 >> 3)) << 3);

    const float* g_be2 = (const float*)(gw + OFF_BE2);
    const float* g_bc1 = (const float*)(gw + OFF_BC1);
    const float* g_wc2 = (const float*)(gw + OFF_WC2);
    const float* g_bc2 = (const float*)(gw + OFF_BC2);

    f32x16 accD = {0.f,0.f,0.f,0.f,0.f,0.f,0.f,0.f,
                   0.f,0.f,0.f,0.f,0.f,0.f,0.f,0.f};

    // pipeline: chunk 0's Pj lines in flight before the barrier
    sh8 g0v = *(const sh8*)(Pst0);
    sh8 g1v = *(const sh8*)(Pst1);

    // swizzled cc read offsets (granule g at physical g ^ (e31>>3), +4*hi shorts)
    int sx = e31 >> 3;
    const unsigned short* ccb = stg + e31 * 40 + 4 * hi;

    __syncthreads();   // staged weights visible

    #pragma unroll 1
    for (int ch = 0; ch < 17; ++ch){
        int c0 = ch * 32;
        *(sh8*)sw0 = g0v;                                  // ds_write_b128 x2
        *(sh8*)sw1 = g1v;
        if (ch < 16){   // issue next chunk's lines now; latency hides under body
            g0v = *(const sh8*)(Pst0 + c0 + 32);
            g1v = *(const sh8*)(Pst1 + c0 + 32);
        }

        unsigned short piS = Pirow[c0 + e31];
        sh8 afrag = *(const sh8*)(gw + OFF_W1AB + (size_t)(hi * 544 + c0 + e31) * 8);
        afrag[1] = hi ? (short)piS : afrag[1];            // Pi into k=9 slot

        // C-init = Pj (same-wave DS pipe is in-order: reads see the writes)
        f32x16 cc;
        #pragma unroll
        for (int g = 0; g < 4; ++g){
            us4 pj = *(const us4*)(ccb + ((g ^ sx) << 3));
            cc[4*g+0] = us2f(pj.x);
            cc[4*g+1] = us2f(pj.y);
            cc[4*g+2] = us2f(pj.z);
            cc[4*g+3] = us2f(pj.w);
        }
        f32x16 h = __builtin_amdgcn_mfma_f32_32x32x16_bf16(afrag, bfragC, cc, 0, 0, 0);

        // silu -> bf16 pairs; lane holds (edge=e31, ch pairs at +4*hi)
        unsigned u0 = pkbf(silu_f(h[0]),  silu_f(h[1]));
        unsigned u1 = pkbf(silu_f(h[2]),  silu_f(h[3]));
        unsigned u2 = pkbf(silu_f(h[4]),  silu_f(h[5]));
        unsigned u3 = pkbf(silu_f(h[6]),  silu_f(h[7]));
        unsigned u4 = pkbf(silu_f(h[8]),  silu_f(h[9]));
        unsigned u5 = pkbf(silu_f(h[10]), silu_f(h[11]));
        unsigned u6 = pkbf(silu_f(h[12]), silu_f(h[13]));
        unsigned u7 = pkbf(silu_f(h[14]), silu_f(h[15]));
        // in-register h^T A-frag: swap lower/upper wave halves
        plswap(u0, u2); plswap(u1, u3);    // K-half ch c0+0..15
        plswap(u4, u6); plswap(u5, u7);    // K-half ch c0+16..31
        sh8 A1 = mk8(u0, u1, u2, u3);
        sh8 A2 = mk8(u4, u5, u6, u7);

        // B = We2 from LDS: B[k=ch][col=out o]; cols 16-31 clamp to rows 0-15
        const unsigned short* wrow = &sh.e.sWe2[(size_t)(e31 & 15) * 552 + c0 + (hi << 3)];
        sh8 B1 = *(const sh8*)(wrow);
        sh8 B2 = *(const sh8*)(wrow + 16);
        accD = __builtin_amdgcn_mfma_f32_32x32x16_bf16(A1, B1, accD, 0, 0, 0);
        accD = __builtin_amdgcn_mfma_f32_32x32x16_bf16(A2, B2, accD, 0, 0, 0);
    }

    // ---- m = silu(OUT2 + be2): lane = out channel o (o<16 valid),
    //      rows = edges (r&3)+8*(r>>2)+4*hi ----
    float be2v = g_be2[e31 & 15];
    float mval[16];
    float msum = 0.f;
    #pragma unroll
    for (int r = 0; r < 16; ++r){
        mval[r] = silu_f(accD[r] + be2v);
        msum += mval[r];
    }
    msum += __shfl_xor(msum, 32);        // partner holds complementary edges

    if (e31 < 16){
        // one-time transpose into sM[edge][o] (bf16), for phase E's B-frags
        #pragma unroll
        for (int r = 0; r < 16; ++r){
            int edge = (r & 3) + 8 * (r >> 2) + 4 * hi;
            stg[edge * 16 + e31] = f2us(mval[r]);
        }
        if (hi == 0)
            mi_out[(size_t)gnode * MD + e31] = msum;   // 16 coalesced stores
    }

    // ---- phase E: coors MLP (reads sM written above; same-wave DS order) ----
    float tsum0 = 0.f, tsum1 = 0.f;
    #pragma unroll
    for (int ut = 0; ut < 4; ++ut){
        sh8 wa3 = *(const sh8*)(gw + OFF_WC1A + (size_t)(ut * 16 + e15) * 32 + q * 8);
        sh8 b0  = (q < 2) ? *(const sh8*)&stg[e15 * 16 + q * 8]        : (sh8)0;
        sh8 b1  = (q < 2) ? *(const sh8*)&stg[(16 + e15) * 16 + q * 8] : (sh8)0;
        fx4 a0 = {0.f,0.f,0.f,0.f};
        fx4 a1 = {0.f,0.f,0.f,0.f};
        a0 = __builtin_amdgcn_mfma_f32_16x16x32_bf16(wa3, b0, a0, 0, 0, 0);
        a1 = __builtin_amdgcn_mfma_f32_16x16x32_bf16(wa3, b1, a1, 0, 0, 0);
        fx4 bc1q = *(const fx4*)&g_bc1[ut * 16 + q * 4];
        fx4 wcq  = *(const fx4*)&g_wc2[ut * 16 + q * 4];
        #pragma unroll
        for (int r = 0; r < 4; ++r){
            tsum0 += silu_f(a0[r] + bc1q[r]) * wcq[r];
            tsum1 += silu_f(a1[r] + bc1q[r]) * wcq[r];
        }
    }
    tsum0 += __shfl_xor(tsum0, 16); tsum0 += __shfl_xor(tsum0, 32);
    tsum1 += __shfl_xor(tsum1, 16); tsum1 += __shfl_xor(tsum1, 32);
    float cw = ((lane < 16) ? tsum0 : tsum1) + g_bc2[0];

    // lanes 0..31 hold edges 0..31; mask the duplicate upper half
    float en = (lane < 32) ? 1.f : 0.f;
    float cx2 = en * cw * rx, cy2 = en * cw * ry, cz2 = en * cw * rz;
    #pragma unroll
    for (int off = 1; off <= 32; off <<= 1){
        cx2 += __shfl_xor(cx2, off);
        cy2 += __shfl_xor(cy2, off);
        cz2 += __shfl_xor(cz2, off);
    }
    if (lane == 0){
        size_t base = (size_t)NODES * DIM + (size_t)gnode * 3;
        if (*flagp){
            float* o = (float*)dout;
            o[base+0] = cx2 + qx; o[base+1] = cy2 + qy; o[base+2] = cz2 + qz;
        } else {
            bf16* o = (bf16*)dout;
            o[base+0] = f2b(cx2 + qx); o[base+1] = f2b(cy2 + qy); o[base+2] = f2b(cz2 + qz);
        }
    }
}

// ---------------------------------------------------------------- K4: node MLP (R5/R8 verbatim, 1024 blocks)
__global__ __launch_bounds__(256) void node_kernel(
        const void* __restrict__ featsRaw, const float* __restrict__ m_i,
        const float* __restrict__ Wn1,   const float* __restrict__ bn1,
        const float* __restrict__ Wn2,   const float* __restrict__ bn2,
        void* __restrict__ dout,         const int* __restrict__ flagp){
    __shared__ __align__(16) float X[8][144];
    __shared__ __align__(16) float Hs[8][256];
    int t = threadIdx.x;
    int g0 = blockIdx.x << 3;
    int fl = flagp[0];

    for (int e = t; e < 8 * DIM; e += 256){
        int nd = e >> 7, c = e & 127;
        size_t off = (size_t)(g0 + nd) * DIM + c;
        X[nd][c] = fl ? ((const float*)featsRaw)[off]
                      : b2f(((const bf16*)featsRaw)[off]);
    }
    if (t < 128){
        int nd = t >> 4, c = t & 15;
        X[nd][DIM + c] = m_i[(size_t)(g0 + nd) * MD + c];
    }
    __syncthreads();

    float acc[8] = {};
    for (int r4 = 0; r4 < 144; r4 += 4){
        float w0 = Wn1[(size_t)(r4+0) * 256 + t];
        float w1 = Wn1[(size_t)(r4+1) * 256 + t];
        float w2 = Wn1[(size_t)(r4+2) * 256 + t];
        float w3 = Wn1[(size_t)(r4+3) * 256 + t];
        #pragma unroll
        for (int nd = 0; nd < 8; ++nd){
            fx4 x4 = *(const fx4*)&X[nd][r4];          // ds_read_b128
            acc[nd] += x4[0]*w0 + x4[1]*w1 + x4[2]*w2 + x4[3]*w3;
        }
    }
    float bb = bn1[t];
    #pragma unroll
    for (int nd = 0; nd < 8; ++nd) Hs[nd][t] = silu_f(acc[nd] + bb);
    __syncthreads();

    int c = t & 127, g = t >> 7;
    float a2[4] = {};
    for (int r4 = 0; r4 < 256; r4 += 4){
        float w0 = Wn2[(size_t)(r4+0) * DIM + c];
        float w1 = Wn2[(size_t)(r4+1) * DIM + c];
        float w2 = Wn2[(size_t)(r4+2) * DIM + c];
        float w3 = Wn2[(size_t)(r4+3) * DIM + c];
        #pragma unroll
        for (int u = 0; u < 4; ++u){
            fx4 h4 = *(const fx4*)&Hs[g*4 + u][r4];    // ds_read_b128
            a2[u] += h4[0]*w0 + h4[1]*w1 + h4[2]*w2 + h4[3]*w3;
        }
    }
    float b2v = bn2[c];
    #pragma unroll
    for (int u = 0; u < 4; ++u){
        int nd = g*4 + u;
        float v = a2[u] + b2v + X[nd][c];
        size_t off2 = (size_t)(g0 + nd) * DIM + c;
        if (fl) ((float*)dout)[off2] = v;
        else    ((bf16*)dout)[off2]  = f2b(v);
    }
}

// ---------------------------------------------------------------- launch
extern "C" void kernel_launch(void* const* d_in, const int* in_sizes, int n_in,
                              void* d_out, int out_size, void* d_ws, size_t ws_size,
                              hipStream_t stream){
    char* ws = (char*)d_ws;
    size_t off = 0;
    auto alloc = [&](size_t bytes) -> char* {
        off = (off + 511) & ~(size_t)511;
        char* p = ws + off;
        off += bytes;
        return p;
    };

    int* flags = (int*)alloc(14 * 4);
    unsigned short* gwimg = (unsigned short*)alloc((size_t)WIMG_SH * 2);
    unsigned short* We1T  = (unsigned short*)alloc((size_t)1088 * 128 * 2);
    unsigned short* fBF   = (unsigned short*)alloc((size_t)NODES * DIM * 2);
    float* coorsF = (float*)alloc((size_t)2 * NN * 3 * 4);
    float* be1F   = (float*)alloc((size_t)544 * 4);
    float* Wn1F   = (float*)alloc((size_t)144 * 256 * 4);
    float* bn1F   = (float*)alloc((size_t)256 * 4);
    float* Wn2F   = (float*)alloc((size_t)256 * 128 * 4);
    float* bn2F   = (float*)alloc((size_t)128 * 4);
    float* coorsS = (float*)alloc((size_t)3 * NODES * 4);   // SoA planes x|y|z
    unsigned short* P = (unsigned short*) alloc((size_t)NODES * PROW * 2);  // 17.8 MB
    float* mi     = (float*)alloc((size_t)NODES * MD * 4);

    Ptrs ps;
    for (int i = 0; i < 14; ++i){ ps.p[i] = d_in[i]; ps.n[i] = in_sizes[i]; }

    detect_kernel<<<14, 256, 0, stream>>>(ps, flags);
    prep_all<<<(PREP_TOTAL + 255) / 256, 256, 0, stream>>>(
        ps, flags, gwimg, We1T, fBF, coorsF, be1F, Wn1F, bn1F, Wn2F, bn2F, coorsS);
    p_gemm<<<dim3(64, 34), 256, 0, stream>>>(fBF, We1T, be1F, P);
    edge_knn<<<NODES/8, 512, 0, stream>>>(coorsF, coorsS, gwimg, P, mi,
                                          d_out, flags + 0);
    node_kernel<<<1024, 256, 0, stream>>>(d_in[0], mi, Wn1F, bn1F, Wn2F, bn2F,
                                          d_out, flags + 0);
}

// Round 13
// 250.841 us; speedup vs baseline: 1.2713x; 1.1311x over previous
//
#include <hip/hip_runtime.h>
#include <hip/hip_bf16.h>
#include <stdint.h>

typedef __hip_bfloat16 bf16;

using sh8    = __attribute__((ext_vector_type(8)))  short;
using sh4    = __attribute__((ext_vector_type(4)))  short;
using us4    = __attribute__((ext_vector_type(4)))  unsigned short;
using f32x16 = __attribute__((ext_vector_type(16))) float;
using fx4    = __attribute__((ext_vector_type(4)))  float;
using i32x2  = __attribute__((ext_vector_type(2)))  int;

#define NN    4096
#define NODES 8192
#define DIM   128
#define MD    16
#define KNNK  32
#define H1N   530
#define CPAD  544      // H1N padded to 17*32
#define PROW  1088     // [Pi 544 | Pj 544] per node, bf16

// weight-image offsets (in shorts)
#define OFF_W1AB 0      // [2][544][8]: half0 = W1f rows f0..7; half1 = [W1f8,0..0]
#define OFF_WE2A 8704   // [o][c] s=552  8832
#define OFF_WC1A 17536  // [u][k] s=32   2048
#define OFF_BE2  19584  // fp32[16]        32
#define OFF_BC1  19616  // fp32[64]       128
#define OFF_WC2  19744  // fp32[64]       128
#define OFF_BC2  19872  // fp32[4]          8
#define WIMG_SH  19880

__device__ __forceinline__ float b2f(bf16 x){ return __bfloat162float(x); }
__device__ __forceinline__ bf16  f2b(float x){ return __float2bfloat16(x); }
// fast silu: v_rcp_f32 (~1 ulp) instead of IEEE division
__device__ __forceinline__ float silu_f(float x){
    return x * __builtin_amdgcn_rcpf(1.f + __expf(-x));
}

__device__ __forceinline__ unsigned short f2us(float f){
    unsigned x = __float_as_uint(f);
    unsigned r = x + 0x7FFFu + ((x >> 16) & 1u);
    return (unsigned short)(r >> 16);
}
__device__ __forceinline__ float us2f(unsigned short u){
    return __uint_as_float(((unsigned)u) << 16);
}
// packed fp32x2 -> bf16x2; low short = a
__device__ __forceinline__ unsigned pkbf(float a, float b){
    __hip_bfloat162 v = __float22bfloat162_rn(make_float2(a, b));
    return *(unsigned*)&v;
}
// v_permlane32_swap_b32: new_a = [a.lo | b.lo], new_b = [a.hi | b.hi]
__device__ __forceinline__ void plswap(unsigned &a, unsigned &b){
    i32x2 r = __builtin_amdgcn_permlane32_swap((int)a, (int)b, false, false);
    a = (unsigned)r[0]; b = (unsigned)r[1];
}
__device__ __forceinline__ sh8 mk8(unsigned a, unsigned b, unsigned c, unsigned d){
    union { unsigned u[4]; sh8 s; } x;
    x.u[0] = a; x.u[1] = b; x.u[2] = c; x.u[3] = d;
    return x.s;
}
// flag-inline dtype read: fl=1 -> fp32 source, fl=0 -> bf16 source
__device__ __forceinline__ float ldconv(const void* p, int fl, size_t i){
    return fl ? ((const float*)p)[i] : b2f(((const bf16*)p)[i]);
}

struct Ptrs { const void* p[14]; int n[14]; };

// ---------------------------------------------------------------- K0: dtype detect
__global__ __launch_bounds__(256) void detect_kernel(Ptrs ps, int* flags){
    int tn = blockIdx.x;
    const bf16* s = (const bf16*)ps.p[tn];
    int n = ps.n[tn]; if (n > 8192) n = 8192;
    int bad = 0;
    for (int i = threadIdx.x; i < n; i += 256){
        float v = b2f(s[i]);
        if (!(fabsf(v) <= 64.f)) bad = 1;   // catches NaN/Inf too
    }
    __shared__ int sbad;
    if (threadIdx.x == 0) sbad = 0;
    __syncthreads();
    if (bad) atomicOr(&sbad, 1);
    __syncthreads();
    if (threadIdx.x == 0) flags[tn] = sbad;   // 1 = fp32, 0 = bf16
}

// ---------------------------------------------------------------- K1: prep_all (R5 verbatim)
#define PREP_TOTAL 1340352
__global__ __launch_bounds__(256) void prep_all(Ptrs ps, const int* __restrict__ flags,
        unsigned short* __restrict__ gwimg, unsigned short* __restrict__ We1T,
        unsigned short* __restrict__ fBF,   float* __restrict__ coorsF,
        float* __restrict__ be1F,  float* __restrict__ Wn1F,
        float* __restrict__ bn1F,  float* __restrict__ Wn2F,
        float* __restrict__ bn2F,  float* __restrict__ coorsS){
    int gid = blockIdx.x * 256 + threadIdx.x;
    if (gid < 4352){                         // W1AB half0: [c][f0..7]
        int c = gid >> 3, f = gid & 7;
        gwimg[OFF_W1AB + gid] =
            (c < H1N) ? f2us(ldconv(ps.p[2], flags[2], (size_t)(256 + f) * H1N + c)) : 0;
    } else if (gid < 8704){                  // W1AB half1: [c][W1f8,0,...]
        int e = gid - 4352; int c = e >> 3, jj = e & 7;
        gwimg[OFF_W1AB + 4352 + e] =
            (jj == 0 && c < H1N) ? f2us(ldconv(ps.p[2], flags[2], (size_t)264 * H1N + c)) : 0;
    } else if (gid < 17536){                 // We2^T s=552
        int e = gid - 8704; int o = e / 552, c = e - o * 552;
        gwimg[OFF_WE2A + e] =
            (c < H1N) ? f2us(ldconv(ps.p[4], flags[4], (size_t)c * 16 + o)) : 0;
    } else if (gid < 19584){                 // Wc1^T s=32
        int e = gid - 17536; int u = e >> 5, k = e & 31;
        gwimg[OFF_WC1A + e] =
            (k < 16) ? f2us(ldconv(ps.p[6], flags[6], (size_t)k * 64 + u)) : 0;
    } else if (gid < 19600){
        ((float*)(gwimg + OFF_BE2))[gid - 19584] = ldconv(ps.p[5], flags[5], gid - 19584);
    } else if (gid < 19664){
        ((float*)(gwimg + OFF_BC1))[gid - 19600] = ldconv(ps.p[7], flags[7], gid - 19600);
    } else if (gid < 19728){
        ((float*)(gwimg + OFF_WC2))[gid - 19664] = ldconv(ps.p[8], flags[8], gid - 19664);
    } else if (gid < 19732){
        int z = gid - 19728;
        ((float*)(gwimg + OFF_BC2))[z] = (z == 0) ? ldconv(ps.p[9], flags[9], 0) : 0.f;
    } else if (gid >= 32768 && gid < 172032){
        int e = gid - 32768; int n = e >> 7, k = e & 127;
        float v;
        if (n < CPAD) v = (n < H1N) ? ldconv(ps.p[2], flags[2], (size_t)k * H1N + n) : 0.f;
        else { int n2 = n - CPAD;
               v = (n2 < H1N) ? ldconv(ps.p[2], flags[2], (size_t)(128 + k) * H1N + n2) : 0.f; }
        We1T[e] = f2us(v);
    } else if (gid >= 172032 && gid < 1220608){
        int e = gid - 172032;
        fBF[e] = f2us(ldconv(ps.p[0], flags[0], e));
    } else if (gid >= 1220608 && gid < 1245184){
        int e = gid - 1220608;
        coorsF[e] = ldconv(ps.p[1], flags[1], e);
    } else if (gid >= 1245184 && gid < 1245714){
        int e = gid - 1245184;
        be1F[e] = ldconv(ps.p[3], flags[3], e);
    } else if (gid >= 1245760 && gid < 1282624){
        int e = gid - 1245760;
        Wn1F[e] = ldconv(ps.p[10], flags[10], e);
    } else if (gid >= 1282624 && gid < 1282880){
        int e = gid - 1282624;
        bn1F[e] = ldconv(ps.p[11], flags[11], e);
    } else if (gid >= 1282880 && gid < 1315648){
        int e = gid - 1282880;
        Wn2F[e] = ldconv(ps.p[12], flags[12], e);
    } else if (gid >= 1315648 && gid < 1315776){
        int e = gid - 1315648;
        bn2F[e] = ldconv(ps.p[13], flags[13], e);
    } else if (gid >= 1315776 && gid < 1340352){
        int e = gid - 1315776;            // source linear: ((b*NN+i)*3 + c)
        int n = e / 3, c = e - n * 3;     // n = global node, c = component
        coorsS[(size_t)c * NODES + n] = ldconv(ps.p[1], flags[1], e);
    }
}

// ---------------------------------------------------------------- K2: P-GEMM (R5 verbatim)
__global__ __launch_bounds__(256) void p_gemm(const unsigned short* __restrict__ fBF,
                                              const unsigned short* __restrict__ We1T,
                                              const float* __restrict__ be1,
                                              unsigned short* __restrict__ P){
    int t = threadIdx.x, lane = t & 63, wid = t >> 6;
    int e31 = lane & 31, hi = lane >> 5;
    int mW = (blockIdx.x << 7) + (wid << 5);
    int n0 = blockIdx.y << 5;

    const unsigned short* Arow = fBF  + (size_t)(mW + e31) * DIM + hi * 8;
    const unsigned short* Brow = We1T + (size_t)(n0 + e31) * DIM + hi * 8;

    f32x16 acc = {0.f,0.f,0.f,0.f,0.f,0.f,0.f,0.f,0.f,0.f,0.f,0.f,0.f,0.f,0.f,0.f};
    #pragma unroll
    for (int kc = 0; kc < 8; ++kc){
        sh8 a  = *(const sh8*)(Arow + kc * 16);
        sh8 bv = *(const sh8*)(Brow + kc * 16);
        acc = __builtin_amdgcn_mfma_f32_32x32x16_bf16(a, bv, acc, 0, 0, 0);
    }
    int n = n0 + e31;
    float beadd = 0.f;
    if (n < CPAD) beadd = (n < H1N) ? be1[n] : 0.f;   // fold be1 into Pi half
    #pragma unroll
    for (int g = 0; g < 4; ++g)
        #pragma unroll
        for (int r = 0; r < 4; ++r){
            int m = mW + 8*g + 4*hi + r;
            P[(size_t)m * PROW + n] = f2us(acc[4*g + r] + beadd);
        }
}

// ---------------------------------------------------------------- K3: KNN + edges fused (8 nodes/block)
// R8 configuration (best measured: 250.96 µs total, edge_knn 114.2 µs).
// knn and edge share the SAME wave->node mapping, so knn runs as the head
// phase of the edge block: indices never leave LDS (global idx deleted).
// knn pass 2 recomputes distances from L2-resident SoA coords (both cache
// variants — LDS byte-cache R10, register byte-cache R11/R12 — lost to
// occupancy collapse / scratch spill; recompute is the measured optimum).
__global__ __launch_bounds__(512, 6) void edge_knn(
        const float* __restrict__ coorsF, const float* __restrict__ coorsS,
        const unsigned short* __restrict__ gw,
        const unsigned short* __restrict__ P,
        float* __restrict__ mi_out, void* __restrict__ dout,
        const int* __restrict__ flagp){
    __shared__ __align__(16) union ShU {
        struct { unsigned hist[8][1024]; unsigned long long blist[8][64]; } k;  // 36.9 KB
        struct { unsigned short sWe2[16*552]; unsigned short trans[8][1280]; } e; // 38.1 KB
    } sh;
    __shared__ int idxw[8][32];          // knn output, wave-local
    __shared__ int cntO[8], cntB[8];

    int t = threadIdx.x, lane = t & 63, wid = t >> 6;
    int gnode = (blockIdx.x << 3) + wid;
    int b = gnode >> 12;
    int e31 = lane & 31, hi = lane >> 5;
    int e15 = lane & 15, q  = lane >> 4;

    // ================= phase A: knn (wave-autonomous radix select) =================
    {
        int i = gnode & (NN - 1);
        const float* cx = coorsS + (size_t)b * NN;
        const float* cy = coorsS + NODES + (size_t)b * NN;
        const float* cz = coorsS + 2 * NODES + (size_t)b * NN;

        float qx = cx[i], qy = cy[i], qz = cz[i];

        unsigned* h = &sh.k.hist[wid][0];
        {   // zero private hist: 4 x uint4 per lane (1024 bins)
            uint4* hz = (uint4*)h;
            uint4 z = make_uint4(0,0,0,0);
            #pragma unroll
            for (int zl = 0; zl < 4; ++zl) hz[zl * 64 + lane] = z;
        }
        if (lane == 0){ cntO[wid] = 0; cntB[wid] = 0; }
        asm volatile("" ::: "memory");

        // pass 1: distances -> bucket -> histogram
        for (int s = 0; s < 16; ++s){
            int j0 = (s << 8) + (lane << 2);
            fx4 X = *(const fx4*)(cx + j0);
            fx4 Y = *(const fx4*)(cy + j0);
            fx4 Z = *(const fx4*)(cz + j0);
            #pragma unroll
            for (int k = 0; k < 4; ++k){
                float dx = qx - X[k], dy = qy - Y[k], dz = qz - Z[k];
                float d  = dx*dx + dy*dy + dz*dz;
                float d2 = d * d;
                atomicAdd(&h[__float_as_uint(d2 * d2) >> 22], 1u);
            }
        }
        asm volatile("s_waitcnt lgkmcnt(0)" ::: "memory");

        // intra-wave scan: lane owns bins [lane*16, lane*16+16)
        unsigned S = 0;
        {
            uint4* hz = (uint4*)h;
            #pragma unroll
            for (int g = 0; g < 4; ++g){
                uint4 v = hz[lane * 4 + g];
                S += v.x + v.y + v.z + v.w;
            }
        }
        unsigned scan = S;
        #pragma unroll
        for (int off = 1; off < 64; off <<= 1){
            unsigned nv = __shfl_up(scan, off);
            if (lane >= off) scan += nv;
        }
        unsigned excl = scan - S;
        unsigned long long own = __ballot(excl < KNNK && excl + S >= KNNK);
        int src = __ffsll((unsigned long long)own) - 1;
        unsigned run = excl, Bloc = 0, below_l = 0;
        #pragma unroll
        for (int r = 0; r < 16; ++r){
            unsigned c = h[lane * 16 + r];
            if (run < KNNK && run + c >= KNNK){ Bloc = lane * 16 + r; below_l = run; }
            run += c;
        }
        unsigned B    = __shfl(Bloc, src);
        unsigned below= __shfl(below_l, src);
        unsigned need = KNNK - below;

        // pass 2: recompute, emit strictly-below, push boundary
        int* co = &cntO[wid];
        int* cbn = &cntB[wid];
        unsigned long long* bl = &sh.k.blist[wid][0];
        int* iw = &idxw[wid][0];
        for (int s = 0; s < 16; ++s){
            int j0 = (s << 8) + (lane << 2);
            fx4 X = *(const fx4*)(cx + j0);
            fx4 Y = *(const fx4*)(cy + j0);
            fx4 Z = *(const fx4*)(cz + j0);
            #pragma unroll
            for (int k = 0; k < 4; ++k){
                float dx = qx - X[k], dy = qy - Y[k], dz = qz - Z[k];
                float d  = dx*dx + dy*dy + dz*dz;
                float d2 = d * d;
                unsigned bk = __float_as_uint(d2 * d2) >> 22;
                int j = j0 + k;
                if (bk < B){
                    int pos = atomicAdd(co, 1);
                    iw[pos] = j;
                } else if (bk == B){
                    unsigned long long mk = ((unsigned long long)__float_as_uint(d) << 32)
                                            | (unsigned)j;
                    int p = atomicAdd(cbn, 1);
                    if (p < 64) bl[p] = mk;
                }
            }
        }
        asm volatile("s_waitcnt lgkmcnt(0) vmcnt(0)" ::: "memory");
        int nb = *cbn;   // same-wave LDS in-order

        if (nb <= 64){
            unsigned long long e = (lane < nb) ? bl[lane] : ~0ull;
            for (unsigned r = 0; r < need; ++r){
                unsigned long long m = e;
                #pragma unroll
                for (int off = 32; off > 0; off >>= 1){
                    unsigned long long o = __shfl_xor(m, off);
                    if (o < m) m = o;
                }
                if (lane == 0)
                    iw[below + r] = (int)(unsigned)(m & 0xffffffffull);
                if (e == m) e = ~0ull;
            }
        } else {
            // ~never: boundary bin overflowed the list — exact full-rescan selection
            unsigned long long lastk = 0;
            for (unsigned r = 0; r < need; ++r){
                unsigned long long lmin = ~0ull;
                for (int s = 0; s < 64; ++s){
                    int j = (s << 6) + lane;
                    float dx = qx - cx[j];
                    float dy = qy - cy[j];
                    float dz = qz - cz[j];
                    float d  = dx*dx + dy*dy + dz*dz;
                    float d2 = d * d;
                    if ((__float_as_uint(d2 * d2) >> 22) == B){
                        unsigned long long mk = (((unsigned long long)__float_as_uint(d) << 32)
                                                 | (unsigned)j) + 1ull;
                        if (mk > lastk && mk < lmin) lmin = mk;
                    }
                }
                #pragma unroll
                for (int off = 32; off > 0; off >>= 1){
                    unsigned long long o = __shfl_xor(lmin, off);
                    if (o < lmin) lmin = o;
                }
                if (lane == 0)
                    iw[below + r] = (int)(unsigned)((lmin - 1ull) & 0xffffffffull);
                lastk = lmin;
            }
        }
    }

    __syncthreads();   // ALL waves done with sh.k before sWe2 overwrites it

    {   // stage We2^T (coalesced float4 copy) into the aliased region
        const float4* s1 = (const float4*)(gw + OFF_WE2A);
        float4* d1 = (float4*)sh.e.sWe2;
        for (int e = t; e < 1104; e += 512) d1[e] = s1[e];
    }

    // ================= phase B: edge pipeline =================
    const float* cb = coorsF + (size_t)b * NN * 3;
    int i = gnode & (NN - 1);
    float qx = cb[i*3+0], qy = cb[i*3+1], qz = cb[i*3+2];

    int jme = idxw[wid][e31];            // same-wave write, in-order visible
    float rx = qx - cb[jme*3+0];
    float ry = qy - cb[jme*3+1];
    float rz = qz - cb[jme*3+2];
    float d = rx*rx + ry*ry + rz*rz;

    // fourier: sincos at d/8, then 3 angle doublings (err << bf16 mantissa)
    float s8v, c8v;
    __sincosf(d * 0.125f, &s8v, &c8v);
    float s4  = 2.f*s8v*c8v, c4  = 1.f - 2.f*s8v*s8v;
    float s2a = 2.f*s4*c4,   c2a = 1.f - 2.f*s4*s4;
    float s1a = 2.f*s2a*c2a, c1a = 1.f - 2.f*s2a*s2a;

    unsigned frb[9];
    frb[0] = f2us(s1a); frb[1] = f2us(s2a); frb[2] = f2us(s4); frb[3] = f2us(s8v);
    frb[4] = f2us(c1a); frb[5] = f2us(c2a); frb[6] = f2us(c4); frb[7] = f2us(c8v);
    frb[8] = f2us(d);

    // hi=0: B[k=0..7][e] = fourier; hi=1: B[8][e]=d, B[9][e]=1.0 (Pi slot)
    sh8 bfragC;
    #pragma unroll
    for (int j = 0; j < 8; ++j)
        bfragC[j] = (hi == 0) ? (short)frb[j]
                  : (short)((j == 0) ? frb[8] : (j == 1) ? 0x3F80u : 0u);

    // coalesced Pj staging: lane covers row (lane>>2) and row 16+(lane>>2),
    // 16 B each at quarter (lane&3); 16B granule XOR-swizzled by (row>>3).
    int nbase = gnode & ~(NN - 1);
    int j0 = __shfl(jme, lane >> 2);
    int j1 = __shfl(jme, 16 + (lane >> 2));
    const unsigned short* Pst0 = P + (size_t)(nbase + j0) * PROW + CPAD + (lane & 3) * 8;
    const unsigned short* Pst1 = P + (size_t)(nbase + j1) * PROW + CPAD + (lane & 3) * 8;
    const unsigned short* Pirow = P + (size_t)gnode * PROW;

    unsigned short* stg = &sh.e.trans[wid][0];            // stride 40 shorts
    int r0 = lane >> 2, r1 = 16 + (lane >> 2), qq = lane & 3;
    unsigned short* sw0 = stg + r0 * 40 + ((qq ^ (r0 >> 3)) << 3);
    unsigned short* sw1 = stg + r1 * 40 + ((qq ^ (r1 >> 3)) << 3);

    const float* g_be2 = (const float*)(gw + OFF_BE2);
    const float* g_bc1 = (const float*)(gw + OFF_BC1);
    const float* g_wc2 = (const float*)(gw + OFF_WC2);
    const float* g_bc2 = (const float*)(gw + OFF_BC2);

    f32x16 accD = {0.f,0.f,0.f,0.f,0.f,0.f,0.f,0.f,
                   0.f,0.f,0.f,0.f,0.f,0.f,0.f,0.f};

    // pipeline: chunk 0's Pj lines in flight before the barrier
    sh8 g0v = *(const sh8*)(Pst0);
    sh8 g1v = *(const sh8*)(Pst1);

    // swizzled cc read offsets (granule g at physical g ^ (e31>>3), +4*hi shorts)
    int sx = e31 >> 3;
    const unsigned short* ccb = stg + e31 * 40 + 4 * hi;

    __syncthreads();   // staged weights visible

    #pragma unroll 1
    for (int ch = 0; ch < 17; ++ch){
        int c0 = ch * 32;
        *(sh8*)sw0 = g0v;                                  // ds_write_b128 x2
        *(sh8*)sw1 = g1v;
        if (ch < 16){   // issue next chunk's lines now; latency hides under body
            g0v = *(const sh8*)(Pst0 + c0 + 32);
            g1v = *(const sh8*)(Pst1 + c0 + 32);
        }

        unsigned short piS = Pirow[c0 + e31];
        sh8 afrag = *(const sh8*)(gw + OFF_W1AB + (size_t)(hi * 544 + c0 + e31) * 8);
        afrag[1] = hi ? (short)piS : afrag[1];            // Pi into k=9 slot

        // C-init = Pj (same-wave DS pipe is in-order: reads see the writes)
        f32x16 cc;
        #pragma unroll
        for (int g = 0; g < 4; ++g){
            us4 pj = *(const us4*)(ccb + ((g ^ sx) << 3));
            cc[4*g+0] = us2f(pj.x);
            cc[4*g+1] = us2f(pj.y);
            cc[4*g+2] = us2f(pj.z);
            cc[4*g+3] = us2f(pj.w);
        }
        f32x16 h = __builtin_amdgcn_mfma_f32_32x32x16_bf16(afrag, bfragC, cc, 0, 0, 0);

        // silu -> bf16 pairs; lane holds (edge=e31, ch pairs at +4*hi)
        unsigned u0 = pkbf(silu_f(h[0]),  silu_f(h[1]));
        unsigned u1 = pkbf(silu_f(h[2]),  silu_f(h[3]));
        unsigned u2 = pkbf(silu_f(h[4]),  silu_f(h[5]));
        unsigned u3 = pkbf(silu_f(h[6]),  silu_f(h[7]));
        unsigned u4 = pkbf(silu_f(h[8]),  silu_f(h[9]));
        unsigned u5 = pkbf(silu_f(h[10]), silu_f(h[11]));
        unsigned u6 = pkbf(silu_f(h[12]), silu_f(h[13]));
        unsigned u7 = pkbf(silu_f(h[14]), silu_f(h[15]));
        // in-register h^T A-frag: swap lower/upper wave halves
        plswap(u0, u2); plswap(u1, u3);    // K-half ch c0+0..15
        plswap(u4, u6); plswap(u5, u7);    // K-half ch c0+16..31
        sh8 A1 = mk8(u0, u1, u2, u3);
        sh8 A2 = mk8(u4, u5, u6, u7);

        // B = We2 from LDS: B[k=ch][col=out o]; cols 16-31 clamp to rows 0-15
        const unsigned short* wrow = &sh.e.sWe2[(size_t)(e31 & 15) * 552 + c0 + (hi << 3)];
        sh8 B1 = *(const sh8*)(wrow);
        sh8 B2 = *(const sh8*)(wrow + 16);
        accD = __builtin_amdgcn_mfma_f32_32x32x16_bf16(A1, B1, accD, 0, 0, 0);
        accD = __builtin_amdgcn_mfma_f32_32x32x16_bf16(A2, B2, accD, 0, 0, 0);
    }

    // ---- m = silu(OUT2 + be2): lane = out channel o (o<16 valid),
    //      rows = edges (r&3)+8*(r>>2)+4*hi ----
    float be2v = g_be2[e31 & 15];
    float mval[16];
    float msum = 0.f;
    #pragma unroll
    for (int r = 0; r < 16; ++r){
        mval[r] = silu_f(accD[r] + be2v);
        msum += mval[r];
    }
    msum += __shfl_xor(msum, 32);        // partner holds complementary edges

    if (e31 < 16){
        // one-time transpose into sM[edge][o] (bf16), for phase E's B-frags
        #pragma unroll
        for (int r = 0; r < 16; ++r){
            int edge = (r & 3) + 8 * (r >> 2) + 4 * hi;
            stg[edge * 16 + e31] = f2us(mval[r]);
        }
        if (hi == 0)
            mi_out[(size_t)gnode * MD + e31] = msum;   // 16 coalesced stores
    }

    // ---- phase E: coors MLP (reads sM written above; same-wave DS order) ----
    float tsum0 = 0.f, tsum1 = 0.f;
    #pragma unroll
    for (int ut = 0; ut < 4; ++ut){
        sh8 wa3 = *(const sh8*)(gw + OFF_WC1A + (size_t)(ut * 16 + e15) * 32 + q * 8);
        sh8 b0  = (q < 2) ? *(const sh8*)&stg[e15 * 16 + q * 8]        : (sh8)0;
        sh8 b1  = (q < 2) ? *(const sh8*)&stg[(16 + e15) * 16 + q * 8] : (sh8)0;
        fx4 a0 = {0.f,0.f,0.f,0.f};
        fx4 a1 = {0.f,0.f,0.f,0.f};
        a0 = __builtin_amdgcn_mfma_f32_16x16x32_bf16(wa3, b0, a0, 0, 0, 0);
        a1 = __builtin_amdgcn_mfma_f32_16x16x32_bf16(wa3, b1, a1, 0, 0, 0);
        fx4 bc1q = *(const fx4*)&g_bc1[ut * 16 + q * 4];
        fx4 wcq  = *(const fx4*)&g_wc2[ut * 16 + q * 4];
        #pragma unroll
        for (int r = 0; r < 4; ++r){
            tsum0 += silu_f(a0[r] + bc1q[r]) * wcq[r];
            tsum1 += silu_f(a1[r] + bc1q[r]) * wcq[r];
        }
    }
    tsum0 += __shfl_xor(tsum0, 16); tsum0 += __shfl_xor(tsum0, 32);
    tsum1 += __shfl_xor(tsum1, 16); tsum1 += __shfl_xor(tsum1, 32);
    float cw = ((lane < 16) ? tsum0 : tsum1) + g_bc2[0];

    // lanes 0..31 hold edges 0..31; mask the duplicate upper half
    float en = (lane < 32) ? 1.f : 0.f;
    float cx2 = en * cw * rx, cy2 = en * cw * ry, cz2 = en * cw * rz;
    #pragma unroll
    for (int off = 1; off <= 32; off <<= 1){
        cx2 += __shfl_xor(cx2, off);
        cy2 += __shfl_xor(cy2, off);
        cz2 += __shfl_xor(cz2, off);
    }
    if (lane == 0){
        size_t base = (size_t)NODES * DIM + (size_t)gnode * 3;
        if (*flagp){
            float* o = (float*)dout;
            o[base+0] = cx2 + qx; o[base+1] = cy2 + qy; o[base+2] = cz2 + qz;
        } else {
            bf16* o = (bf16*)dout;
            o[base+0] = f2b(cx2 + qx); o[base+1] = f2b(cy2 + qy); o[base+2] = f2b(cz2 + qz);
        }
    }
}

// ---------------------------------------------------------------- K4: node MLP (R5/R8 verbatim, 1024 blocks)
__global__ __launch_bounds__(256) void node_kernel(
        const void* __restrict__ featsRaw, const float* __restrict__ m_i,
        const float* __restrict__ Wn1,   const float* __restrict__ bn1,
        const float* __restrict__ Wn2,   const float* __restrict__ bn2,
        void* __restrict__ dout,         const int* __restrict__ flagp){
    __shared__ __align__(16) float X[8][144];
    __shared__ __align__(16) float Hs[8][256];
    int t = threadIdx.x;
    int g0 = blockIdx.x << 3;
    int fl = flagp[0];

    for (int e = t; e < 8 * DIM; e += 256){
        int nd = e >> 7, c = e & 127;
        size_t off = (size_t)(g0 + nd) * DIM + c;
        X[nd][c] = fl ? ((const float*)featsRaw)[off]
                      : b2f(((const bf16*)featsRaw)[off]);
    }
    if (t < 128){
        int nd = t >> 4, c = t & 15;
        X[nd][DIM + c] = m_i[(size_t)(g0 + nd) * MD + c];
    }
    __syncthreads();

    float acc[8] = {};
    for (int r4 = 0; r4 < 144; r4 += 4){
        float w0 = Wn1[(size_t)(r4+0) * 256 + t];
        float w1 = Wn1[(size_t)(r4+1) * 256 + t];
        float w2 = Wn1[(size_t)(r4+2) * 256 + t];
        float w3 = Wn1[(size_t)(r4+3) * 256 + t];
        #pragma unroll
        for (int nd = 0; nd < 8; ++nd){
            fx4 x4 = *(const fx4*)&X[nd][r4];          // ds_read_b128
            acc[nd] += x4[0]*w0 + x4[1]*w1 + x4[2]*w2 + x4[3]*w3;
        }
    }
    float bb = bn1[t];
    #pragma unroll
    for (int nd = 0; nd < 8; ++nd) Hs[nd][t] = silu_f(acc[nd] + bb);
    __syncthreads();

    int c = t & 127, g = t >> 7;
    float a2[4] = {};
    for (int r4 = 0; r4 < 256; r4 += 4){
        float w0 = Wn2[(size_t)(r4+0) * DIM + c];
        float w1 = Wn2[(size_t)(r4+1) * DIM + c];
        float w2 = Wn2[(size_t)(r4+2) * DIM + c];
        float w3 = Wn2[(size_t)(r4+3) * DIM + c];
        #pragma unroll
        for (int u = 0; u < 4; ++u){
            fx4 h4 = *(const fx4*)&Hs[g*4 + u][r4];    // ds_read_b128
            a2[u] += h4[0]*w0 + h4[1]*w1 + h4[2]*w2 + h4[3]*w3;
        }
    }
    float b2v = bn2[c];
    #pragma unroll
    for (int u = 0; u < 4; ++u){
        int nd = g*4 + u;
        float v = a2[u] + b2v + X[nd][c];
        size_t off2 = (size_t)(g0 + nd) * DIM + c;
        if (fl) ((float*)dout)[off2] = v;
        else    ((bf16*)dout)[off2]  = f2b(v);
    }
}

// ---------------------------------------------------------------- launch
extern "C" void kernel_launch(void* const* d_in, const int* in_sizes, int n_in,
                              void* d_out, int out_size, void* d_ws, size_t ws_size,
                              hipStream_t stream){
    char* ws = (char*)d_ws;
    size_t off = 0;
    auto alloc = [&](size_t bytes) -> char* {
        off = (off + 511) & ~(size_t)511;
        char* p = ws + off;
        off += bytes;
        return p;
    };

    int* flags = (int*)alloc(14 * 4);
    unsigned short* gwimg = (unsigned short*)alloc((size_t)WIMG_SH * 2);
    unsigned short* We1T  = (unsigned short*)alloc((size_t)1088 * 128 * 2);
    unsigned short* fBF   = (unsigned short*)alloc((size_t)NODES * DIM * 2);
    float* coorsF = (float*)alloc((size_t)2 * NN * 3 * 4);
    float* be1F   = (float*)alloc((size_t)544 * 4);
    float* Wn1F   = (float*)alloc((size_t)144 * 256 * 4);
    float* bn1F   = (float*)alloc((size_t)256 * 4);
    float* Wn2F   = (float*)alloc((size_t)256 * 128 * 4);
    float* bn2F   = (float*)alloc((size_t)128 * 4);
    float* coorsS = (float*)alloc((size_t)3 * NODES * 4);   // SoA planes x|y|z
    unsigned short* P = (unsigned short*) alloc((size_t)NODES * PROW * 2);  // 17.8 MB
    float* mi     = (float*)alloc((size_t)NODES * MD * 4);

    Ptrs ps;
    for (int i = 0; i < 14; ++i){ ps.p[i] = d_in[i]; ps.n[i] = in_sizes[i]; }

    detect_kernel<<<14, 256, 0, stream>>>(ps, flags);
    prep_all<<<(PREP_TOTAL + 255) / 256, 256, 0, stream>>>(
        ps, flags, gwimg, We1T, fBF, coorsF, be1F, Wn1F, bn1F, Wn2F, bn2F, coorsS);
    p_gemm<<<dim3(64, 34), 256, 0, stream>>>(fBF, We1T, be1F, P);
    edge_knn<<<NODES/8, 512, 0, stream>>>(coorsF, coorsS, gwimg, P, mi,
                                          d_out, flags + 0);
    node_kernel<<<1024, 256, 0, stream>>>(d_in[0], mi, Wn1F, bn1F, Wn2F, bn2F,
                                          d_out, flags + 0);
}